// Round 2
// baseline (784.681 us; speedup 1.0000x reference)
//
#include <hip/hip_runtime.h>
#include <hip/hip_bf16.h>

#define BB 16
#define CC 384
#define HH 56
#define WW 56
#define PLANE (HH*WW)
#define NHW (BB*PLANE)

typedef __attribute__((ext_vector_type(8)))  short short8;   // 8 bf16 (4 VGPR) MFMA frag
typedef __attribute__((ext_vector_type(16))) float f32x16;   // 32x32 MFMA accumulator
typedef unsigned int uint;

// ---------------- Kernel 1: 31x31 depthwise conv via MFMA (+5x5 conv, both stored) ----------
// per ky: out-tile[m][n] += A(in rows y0+ky-15+m, cols x0-15+k) x T_ky,
//   T_ky[k][n] = w[ky][k-n] (Toeplitz band), K=64 = 4 x mfma_f32_32x32x16_bf16.
// Weights hi+lo bf16 split (2 MFMAs per A-frag) -> only x-quantization error remains.
// Bands stored as ONE dword per element: (hi | lo<<16). Per-lane band window = 8
// consecutive dwords (dword index = k - n + 32) -> ds_read2_b32 pairs serving BOTH
// bands, unpacked with v_perm_b32. No alignbit/parity handling.
// Block = 4 waves = 4 batch-planes of one channel. Tiles y0,x0 in {0,24}; overlap
// recomputes identically; stats masked.
#define PSTR 92                // 184 B row stride: 46 words == 14 mod 32 -> 2-way (free)
#define PROWS 86               // rows -15..70 (15 zero halo each side)
#define PSZ (PROWS*PSTR)       // 7912 shorts per plane
#define WL_W 100               // dwords per large-band ky row, idx = (k-n) + 32
#define WS_W 80                // dwords per small-band ky row, idx = (k-n) + 31

static __device__ __forceinline__ short f2bf(float f) {
    // RNE float->bf16 (finite inputs only)
    unsigned int u = __float_as_uint(f);
    unsigned int r = (u + 0x7fffu + ((u >> 16) & 1u)) >> 16;
    return (short)r;
}

static __device__ __forceinline__ short8 ldA(const short* ap) {
    // 8 contiguous bf16, 8B-aligned by construction -> 2x ds_read_b64
    union { uint u[4]; short8 v; } r;
    uint2 lo = *(const uint2*)(ap);
    uint2 hi = *(const uint2*)(ap + 4);
    r.u[0] = lo.x; r.u[1] = lo.y; r.u[2] = hi.x; r.u[3] = hi.y;
    return r.v;
}

static __device__ __forceinline__ void ldW2(const uint* p, short8* h, short8* l) {
    // 8 consecutive band dwords (dword-aligned, per-lane offset) -> ds_read2_b32 x4;
    // unpack hi band (low16s) and lo band (high16s) via v_perm_b32.
    union { uint u[4]; short8 v; } H, L;
    #pragma unroll
    for (int i = 0; i < 4; ++i) {
        uint d0 = p[2*i];
        uint d1 = p[2*i + 1];
        H.u[i] = __builtin_amdgcn_perm(d1, d0, 0x05040100u);  // [d0.b0,d0.b1,d1.b0,d1.b1]
        L.u[i] = __builtin_amdgcn_perm(d1, d0, 0x07060302u);  // [d0.b2,d0.b3,d1.b2,d1.b3]
    }
    *h = H.v; *l = L.v;
}

template<bool PACK>
__global__ __launch_bounds__(256, 2) void conv_large_k(
    const float* __restrict__ x, const float* __restrict__ wL,
    const float* __restrict__ wS,
    unsigned short* __restrict__ yL, uint* __restrict__ pk,
    float* __restrict__ stats)
{
    __shared__ __align__(16) short planes[4*PSZ];   // 63296 B
    __shared__ __align__(16) uint  wpL[31*WL_W];    // 12400 B (hi|lo packed)
    __shared__ __align__(16) uint  wpS[5*WS_W];     //  1600 B  -> 77296 B total, 2 blk/CU

    const int bid  = blockIdx.x;
    const int c    = bid % CC;
    const int bg   = bid / CC;          // batch group 0..3
    const int tid  = threadIdx.x;
    const int w    = tid >> 6;          // wave = plane
    const int lane = tid & 63;
    const int m    = lane & 31;         // A-row / B-col / D-col lane field
    const int g    = lane >> 5;         // k-group

    // ---- wave-local zero + stage own plane (bf16, halo zeros) ----
    short* pl = planes + w*PSZ;
    {
        uint4 z = make_uint4(0,0,0,0);
        uint4* p4 = (uint4*)pl;
        #pragma unroll 1
        for (int i = lane; i < PSZ/8; i += 64) p4[i] = z;
    }
    const int b = bg*4 + w;
    const float* xp = x + ((size_t)b*CC + c)*PLANE;
    #pragma unroll 1
    for (int i = lane; i < PLANE; i += 64) {
        int r  = i / WW;
        int cc = i - r*WW;
        pl[(r + 15)*PSTR + cc + 15] = f2bf(xp[i]);
    }

    // ---- cooperative weight-band build (shared by 4 waves, same c) ----
    const float* wrow = wL + c*961;
    #pragma unroll 1
    for (int i = tid; i < 31*WL_W; i += 256) {
        int ky = i / WL_W;
        int j  = i - ky*WL_W;
        int widx = j - 32;
        uint d = 0;
        if (widx >= 0 && widx < 31) {
            float wv = wrow[ky*31 + widx];
            unsigned short hi = (unsigned short)f2bf(wv);
            float res = wv - __uint_as_float((uint)hi << 16);
            unsigned short lo = (unsigned short)f2bf(res);
            d = (uint)hi | ((uint)lo << 16);
        }
        wpL[i] = d;
    }
    const float* wrowS = wS + c*25;
    #pragma unroll 1
    for (int i = tid; i < 5*WS_W; i += 256) {
        int ky = i / WS_W;
        int j  = i - ky*WS_W;
        int widx = j - 32;
        uint d = 0;
        if (widx >= 0 && widx < 5) {
            float wv = wrowS[ky*5 + widx];
            unsigned short hi = (unsigned short)f2bf(wv);
            float res = wv - __uint_as_float((uint)hi << 16);
            unsigned short lo = (unsigned short)f2bf(res);
            d = (uint)hi | ((uint)lo << 16);
        }
        wpS[i] = d;
    }
    __syncthreads();

    // ---- per-lane bases ----
    const int  toff = 8*g - m;                 // band element base = k - n
    const uint* wLd = wpL + (toff + 32);       // >= 1
    const uint* wSd = wpS + (toff + 31);       // >= 0
    const short* abase = pl + m*PSTR + 8*g;

    f32x16 acc[4] = {};                        // tiles (ty,tx), y0/x0 = 24*ty/tx

    // ---- main loop: 31 ky x 4 Ksteps x 4 tiles x (hi,lo) = 992 MFMA ----
    // unroll 2: lets the scheduler hoist ky+1 band/A loads under ky's MFMA block
    #pragma unroll 2
    for (int ky = 0; ky < 31; ++ky) {
        const uint* wk = wLd + ky*WL_W;
        short8 BH[4], BL[4];
        #pragma unroll
        for (int s = 0; s < 4; ++s) ldW2(wk + 16*s, &BH[s], &BL[s]);
        const short* ar = abase + ky*PSTR;
        #pragma unroll
        for (int s = 0; s < 4; ++s) {
            short8 A4[4];
            #pragma unroll
            for (int t = 0; t < 4; ++t) {
                const int ty = t >> 1, tx = t & 1;
                A4[t] = ldA(ar + ty*(24*PSTR) + tx*24 + 16*s);
            }
            #pragma unroll
            for (int t = 0; t < 4; ++t)
                acc[t] = __builtin_amdgcn_mfma_f32_32x32x16_bf16(A4[t], BH[s], acc[t], 0, 0, 0);
            #pragma unroll
            for (int t = 0; t < 4; ++t)
                acc[t] = __builtin_amdgcn_mfma_f32_32x32x16_bf16(A4[t], BL[s], acc[t], 0, 0, 0);
        }
    }

    // ---- epilogue: per tile {5x5 hi+lo MFMA, masked stats, packed store} ----
    float sL = 0.f, sL2 = 0.f, sS = 0.f, sS2 = 0.f;
    unsigned short* yout = yL + ((size_t)b*CC + c)*PLANE;
    uint*           pout = pk + ((size_t)b*CC + c)*PLANE;

    #pragma unroll
    for (int t = 0; t < 4; ++t) {
        const int ty = t >> 1, tx = t & 1;
        // small conv: k = n + kx + 1 in [1,36] -> 3 Ksteps; A col base = x0 + 12 (8B-aligned)
        f32x16 aS_ = {};
        const short* asb = abase + (ty*24 + 13)*PSTR + tx*24 + 12;
        #pragma unroll
        for (int k2 = 0; k2 < 5; ++k2) {
            const uint* wk2 = wSd + k2*WS_W;
            const short* ar2 = asb + k2*PSTR;
            #pragma unroll
            for (int s = 0; s < 3; ++s) {
                short8 bh, bl;
                ldW2(wk2 + 16*s, &bh, &bl);
                short8 av = ldA(ar2 + 16*s);
                aS_ = __builtin_amdgcn_mfma_f32_32x32x16_bf16(av, bh, aS_, 0, 0, 0);
                aS_ = __builtin_amdgcn_mfma_f32_32x32x16_bf16(av, bl, aS_, 0, 0, 0);
            }
        }
        // stats masked so the 24/32 tile overlap isn't double counted
        const float cm = (tx == 0 || m >= 8) ? 1.f : 0.f;
        #pragma unroll
        for (int r = 0; r < 16; ++r) {
            float v  = acc[t][r];
            float v2 = aS_[r];
            if (ty == 0 || r >= 4) {
                sL  = fmaf(cm, v,   sL);
                sL2 = fmaf(cm, v*v, sL2);
                sS  = fmaf(cm, v2,    sS);
                sS2 = fmaf(cm, v2*v2, sS2);
            }
            const int row = (r & 3) + 8*(r >> 2) + 4*g;  // C/D: col=lane&31
            const int ofs = (ty*24 + row)*WW + tx*24 + m;
            if (PACK) {
                pout[ofs] = (uint)(unsigned short)f2bf(v) | ((uint)(unsigned short)f2bf(v2) << 16);
            } else {
                yout[ofs] = (unsigned short)f2bf(v);
            }
        }
    }

    // ---- wave reduce + atomics (per wave = per plane) ----
    #pragma unroll
    for (int off = 32; off > 0; off >>= 1) {
        sL  += __shfl_down(sL,  off);
        sL2 += __shfl_down(sL2, off);
        sS  += __shfl_down(sS,  off);
        sS2 += __shfl_down(sS2, off);
    }
    if (lane == 0) {
        atomicAdd(&stats[c],        sL);
        atomicAdd(&stats[CC + c],   sL2);
        atomicAdd(&stats[2*CC + c], sS);
        atomicAdd(&stats[3*CC + c], sS2);
    }
}

// ---------------- Kernel 2 (packed path): pure streaming affine combine ----------------
__global__ __launch_bounds__(256) void fuse_pack_k(
    const uint* __restrict__ pk, const float* __restrict__ stats,
    const float* __restrict__ gL, const float* __restrict__ bL,
    const float* __restrict__ gS, const float* __restrict__ bS,
    float* __restrict__ out)
{
    const int bid = blockIdx.x;
    const int c   = bid % CC;
    const int tid = threadIdx.x;

    const float inv_n = 1.0f / (float)NHW;
    float mL = stats[c]          * inv_n;
    float vL = stats[CC + c]     * inv_n - mL * mL;
    float aL = rsqrtf(vL + 1e-5f) * gL[c];
    float mS = stats[2*CC + c]   * inv_n;
    float vS = stats[3*CC + c]   * inv_n - mS * mS;
    float aS = rsqrtf(vS + 1e-5f) * gS[c];
    float cst = bL[c] + bS[c] - mL * aL - mS * aS;

    const uint4* pp = (const uint4*)(pk + (size_t)bid * PLANE);
    float4*      op = (float4*)(out + (size_t)bid * PLANE);
    #pragma unroll 1
    for (int t = tid; t < PLANE/4; t += 256) {
        uint4 v = pp[t];
        float4 r;
        r.x = fmaf(aL, __uint_as_float(v.x << 16), fmaf(aS, __uint_as_float(v.x & 0xffff0000u), cst));
        r.y = fmaf(aL, __uint_as_float(v.y << 16), fmaf(aS, __uint_as_float(v.y & 0xffff0000u), cst));
        r.z = fmaf(aL, __uint_as_float(v.z << 16), fmaf(aS, __uint_as_float(v.z & 0xffff0000u), cst));
        r.w = fmaf(aL, __uint_as_float(v.w << 16), fmaf(aS, __uint_as_float(v.w & 0xffff0000u), cst));
        op[t] = r;
    }
}

// ---------------- Kernel 2 (fallback, ws too small): fp32 5x5 + affine ----------------
#define ST3 61
__global__ __launch_bounds__(256) void fuse_small_k(
    const float* __restrict__ x, const float* __restrict__ wS,
    const unsigned short* __restrict__ yL, const float* __restrict__ stats,
    const float* __restrict__ gL, const float* __restrict__ bL,
    const float* __restrict__ gS, const float* __restrict__ bS,
    float* __restrict__ out)
{
    __shared__ float in_s[60 * ST3];

    const int bid = blockIdx.x;
    const int c   = bid % CC;
    const int tid = threadIdx.x;
    const float* __restrict__ w2 = wS + c * 25;

    for (int i = tid; i < 60 * ST3; i += 256) in_s[i] = 0.f;
    __syncthreads();

    const float4* xp4 = (const float4*)(x + (size_t)bid * PLANE);
    for (int t = tid; t < PLANE / 4; t += 256) {
        int r  = t / (WW / 4);
        int c4 = (t - r * (WW / 4)) * 4;
        float4 v = xp4[t];
        float* dst = &in_s[(r + 2) * ST3 + 2 + c4];
        dst[0] = v.x; dst[1] = v.y; dst[2] = v.z; dst[3] = v.w;
    }
    __syncthreads();

    const float inv_n = 1.0f / (float)NHW;
    float mL = stats[c]          * inv_n;
    float vL = stats[CC + c]     * inv_n - mL * mL;
    float aL = rsqrtf(vL + 1e-5f) * gL[c];
    float mS = stats[2*CC + c]   * inv_n;
    float vS = stats[3*CC + c]   * inv_n - mS * mS;
    float aS = rsqrtf(vS + 1e-5f) * gS[c];
    float cst = bL[c] + bS[c] - mL * aL - mS * aS;

    const unsigned short* yp = yL + (size_t)bid * PLANE;
    float* op = out + (size_t)bid * PLANE;

    #pragma unroll 1
    for (int t = tid; t < PLANE / 4; t += 256) {
        int r  = t / 14;
        int c4 = (t - r * 14) * 4;
        float o0 = 0.f, o1 = 0.f, o2 = 0.f, o3 = 0.f;
        #pragma unroll
        for (int ky = 0; ky < 5; ++ky) {
            const float* rp = &in_s[(r + ky) * ST3 + c4];
            float f[9];
            #pragma unroll
            for (int j = 0; j < 9; ++j) f[j] = rp[j];
            const float* wr = w2 + ky * 5;
            #pragma unroll
            for (int kx = 0; kx < 5; ++kx) {
                float wv = wr[kx];
                o0 = fmaf(f[kx + 0], wv, o0);
                o1 = fmaf(f[kx + 1], wv, o1);
                o2 = fmaf(f[kx + 2], wv, o2);
                o3 = fmaf(f[kx + 3], wv, o3);
            }
        }
        ushort4 yv = *(const ushort4*)(yp + 4 * t);
        float4 res;
        res.x = fmaf(aL, __uint_as_float(((uint)yv.x) << 16), fmaf(aS, o0, cst));
        res.y = fmaf(aL, __uint_as_float(((uint)yv.y) << 16), fmaf(aS, o1, cst));
        res.z = fmaf(aL, __uint_as_float(((uint)yv.z) << 16), fmaf(aS, o2, cst));
        res.w = fmaf(aL, __uint_as_float(((uint)yv.w) << 16), fmaf(aS, o3, cst));
        *(float4*)(op + 4 * t) = res;
    }
}

extern "C" void kernel_launch(void* const* d_in, const int* in_sizes, int n_in,
                              void* d_out, int out_size, void* d_ws, size_t ws_size,
                              hipStream_t stream) {
    const float* x  = (const float*)d_in[0];
    const float* wL = (const float*)d_in[1];
    const float* gL = (const float*)d_in[2];
    const float* bL = (const float*)d_in[3];
    const float* wS = (const float*)d_in[4];
    const float* gS = (const float*)d_in[5];
    const float* bS = (const float*)d_in[6];
    float* out = (float*)d_out;

    const size_t pk_bytes = (size_t)BB * CC * PLANE * sizeof(uint);           // 77 MB
    const size_t yl_bytes = (size_t)BB * CC * PLANE * sizeof(unsigned short); // 38.5 MB
    const bool pack = ws_size >= pk_bytes + 4 * CC * sizeof(float);

    if (pack) {
        uint* pkbuf  = (uint*)d_ws;
        float* stats = (float*)((char*)d_ws + pk_bytes);
        hipMemsetAsync(stats, 0, 4 * CC * sizeof(float), stream);
        conv_large_k<true><<<4 * CC, 256, 0, stream>>>(x, wL, wS, (unsigned short*)d_ws, pkbuf, stats);
        fuse_pack_k<<<BB * CC, 256, 0, stream>>>(pkbuf, stats, gL, bL, gS, bS, out);
    } else {
        unsigned short* yLbuf = (unsigned short*)d_ws;
        float* stats = (float*)((char*)d_ws + yl_bytes);
        hipMemsetAsync(stats, 0, 4 * CC * sizeof(float), stream);
        conv_large_k<false><<<4 * CC, 256, 0, stream>>>(x, wL, wS, yLbuf, (uint*)d_ws, stats);
        fuse_small_k<<<BB * CC, 256, 0, stream>>>(x, wS, yLbuf, stats, gL, bL, gS, bS, out);
    }
}

// Round 3
// 480.413 us; speedup vs baseline: 1.6333x; 1.6333x over previous
//
#include <hip/hip_runtime.h>
#include <hip/hip_bf16.h>

#define BB 16
#define CC 384
#define HH 56
#define WW 56
#define PLANE (HH*WW)
#define NHW (BB*PLANE)

typedef __attribute__((ext_vector_type(8)))  short short8;   // 8 bf16 (4 VGPR) MFMA frag
typedef __attribute__((ext_vector_type(16))) float f32x16;   // 32x32 MFMA accumulator
typedef unsigned int uint;

// ---------------- Kernel 1: 31x31 depthwise conv via MFMA (+5x5 conv, both stored) ----------
// per ky: out-tile[m][n] += A(in rows y0+ky-15+m, cols x0-15+k) x T_ky,
//   T_ky[k][n] = w[ky][k-n] (Toeplitz band), K=64 = 4 x mfma_f32_32x32x16_bf16.
// Weights hi+lo bf16 split (2 MFMAs per A-frag) -> only x-quantization error remains.
// Bands stored as ONE dword per element: (hi | lo<<16). Per-lane band window = 8
// consecutive dwords (dword index = k - n + 32) -> ds_read2_b32 pairs serving BOTH
// bands, unpacked with v_perm_b32.
// NOTE R2 lesson: ky-loop MUST stay unroll 1. unroll 2 doubled live band/A frags on
// top of 64 acc AGPRs -> scratch spill (FETCH 645MB/WRITE 1.3GB, 3x slowdown).
// Block = 4 waves = 4 batch-planes of one channel. Tiles y0,x0 in {0,24}; overlap
// recomputes identically; stats masked.
#define PSTR 92                // 184 B row stride: 46 words == 14 mod 32 -> 2-way (free)
#define PROWS 86               // rows -15..70 (15 zero halo each side)
#define PSZ (PROWS*PSTR)       // 7912 shorts per plane
#define WL_W 100               // dwords per large-band ky row, idx = (k-n) + 32
#define WS_W 80                // dwords per small-band ky row, idx = (k-n) + 31

static __device__ __forceinline__ short f2bf(float f) {
    // RNE float->bf16 (finite inputs only)
    unsigned int u = __float_as_uint(f);
    unsigned int r = (u + 0x7fffu + ((u >> 16) & 1u)) >> 16;
    return (short)r;
}

static __device__ __forceinline__ short8 ldA(const short* ap) {
    // 8 contiguous bf16, 8B-aligned by construction -> 2x ds_read_b64
    union { uint u[4]; short8 v; } r;
    uint2 lo = *(const uint2*)(ap);
    uint2 hi = *(const uint2*)(ap + 4);
    r.u[0] = lo.x; r.u[1] = lo.y; r.u[2] = hi.x; r.u[3] = hi.y;
    return r.v;
}

static __device__ __forceinline__ void ldW2(const uint* p, short8* h, short8* l) {
    // 8 consecutive band dwords (dword-aligned, per-lane offset) -> ds_read2_b32 x4;
    // unpack hi band (low16s) and lo band (high16s) via v_perm_b32.
    union { uint u[4]; short8 v; } H, L;
    #pragma unroll
    for (int i = 0; i < 4; ++i) {
        uint d0 = p[2*i];
        uint d1 = p[2*i + 1];
        H.u[i] = __builtin_amdgcn_perm(d1, d0, 0x05040100u);  // [d0.b0,d0.b1,d1.b0,d1.b1]
        L.u[i] = __builtin_amdgcn_perm(d1, d0, 0x07060302u);  // [d0.b2,d0.b3,d1.b2,d1.b3]
    }
    *h = H.v; *l = L.v;
}

template<bool PACK>
__global__ __launch_bounds__(256, 2) void conv_large_k(
    const float* __restrict__ x, const float* __restrict__ wL,
    const float* __restrict__ wS,
    unsigned short* __restrict__ yL, uint* __restrict__ pk,
    float* __restrict__ stats)
{
    __shared__ __align__(16) short planes[4*PSZ];   // 63296 B
    __shared__ __align__(16) uint  wpL[31*WL_W];    // 12400 B (hi|lo packed)
    __shared__ __align__(16) uint  wpS[5*WS_W];     //  1600 B  -> 77296 B total, 2 blk/CU

    const int bid  = blockIdx.x;
    const int c    = bid % CC;
    const int bg   = bid / CC;          // batch group 0..3
    const int tid  = threadIdx.x;
    const int w    = tid >> 6;          // wave = plane
    const int lane = tid & 63;
    const int m    = lane & 31;         // A-row / B-col / D-col lane field
    const int g    = lane >> 5;         // k-group

    // ---- wave-local zero + stage own plane (bf16, halo zeros) ----
    short* pl = planes + w*PSZ;
    {
        uint4 z = make_uint4(0,0,0,0);
        uint4* p4 = (uint4*)pl;
        #pragma unroll 1
        for (int i = lane; i < PSZ/8; i += 64) p4[i] = z;
    }
    const int b = bg*4 + w;
    const float* xp = x + ((size_t)b*CC + c)*PLANE;
    #pragma unroll 1
    for (int i = lane; i < PLANE; i += 64) {
        int r  = i / WW;
        int cc = i - r*WW;
        pl[(r + 15)*PSTR + cc + 15] = f2bf(xp[i]);
    }

    // ---- cooperative weight-band build (shared by 4 waves, same c) ----
    const float* wrow = wL + c*961;
    #pragma unroll 1
    for (int i = tid; i < 31*WL_W; i += 256) {
        int ky = i / WL_W;
        int j  = i - ky*WL_W;
        int widx = j - 32;
        uint d = 0;
        if (widx >= 0 && widx < 31) {
            float wv = wrow[ky*31 + widx];
            unsigned short hi = (unsigned short)f2bf(wv);
            float res = wv - __uint_as_float((uint)hi << 16);
            unsigned short lo = (unsigned short)f2bf(res);
            d = (uint)hi | ((uint)lo << 16);
        }
        wpL[i] = d;
    }
    const float* wrowS = wS + c*25;
    #pragma unroll 1
    for (int i = tid; i < 5*WS_W; i += 256) {
        int ky = i / WS_W;
        int j  = i - ky*WS_W;
        int widx = j - 32;
        uint d = 0;
        if (widx >= 0 && widx < 5) {
            float wv = wrowS[ky*5 + widx];
            unsigned short hi = (unsigned short)f2bf(wv);
            float res = wv - __uint_as_float((uint)hi << 16);
            unsigned short lo = (unsigned short)f2bf(res);
            d = (uint)hi | ((uint)lo << 16);
        }
        wpS[i] = d;
    }
    __syncthreads();

    // ---- per-lane bases ----
    const int  toff = 8*g - m;                 // band element base = k - n
    const uint* wLd = wpL + (toff + 32);       // >= 1
    const uint* wSd = wpS + (toff + 31);       // >= 0
    const short* abase = pl + m*PSTR + 8*g;

    f32x16 acc[4] = {};                        // tiles (ty,tx), y0/x0 = 24*ty/tx

    // ---- main loop: 31 ky x 4 Ksteps x 4 tiles x (hi,lo) = 992 MFMA ----
    #pragma unroll 1
    for (int ky = 0; ky < 31; ++ky) {
        const uint* wk = wLd + ky*WL_W;
        short8 BH[4], BL[4];
        #pragma unroll
        for (int s = 0; s < 4; ++s) ldW2(wk + 16*s, &BH[s], &BL[s]);
        const short* ar = abase + ky*PSTR;
        #pragma unroll
        for (int s = 0; s < 4; ++s) {
            short8 A4[4];
            #pragma unroll
            for (int t = 0; t < 4; ++t) {
                const int ty = t >> 1, tx = t & 1;
                A4[t] = ldA(ar + ty*(24*PSTR) + tx*24 + 16*s);
            }
            #pragma unroll
            for (int t = 0; t < 4; ++t)
                acc[t] = __builtin_amdgcn_mfma_f32_32x32x16_bf16(A4[t], BH[s], acc[t], 0, 0, 0);
            #pragma unroll
            for (int t = 0; t < 4; ++t)
                acc[t] = __builtin_amdgcn_mfma_f32_32x32x16_bf16(A4[t], BL[s], acc[t], 0, 0, 0);
        }
    }

    // ---- epilogue: per tile {5x5 hi+lo MFMA, masked stats, packed store} ----
    float sL = 0.f, sL2 = 0.f, sS = 0.f, sS2 = 0.f;
    unsigned short* yout = yL + ((size_t)b*CC + c)*PLANE;
    uint*           pout = pk + ((size_t)b*CC + c)*PLANE;

    #pragma unroll
    for (int t = 0; t < 4; ++t) {
        const int ty = t >> 1, tx = t & 1;
        // small conv: k = n + kx + 1 in [1,36] -> 3 Ksteps; A col base = x0 + 12 (8B-aligned)
        f32x16 aS_ = {};
        const short* asb = abase + (ty*24 + 13)*PSTR + tx*24 + 12;
        #pragma unroll
        for (int k2 = 0; k2 < 5; ++k2) {
            const uint* wk2 = wSd + k2*WS_W;
            const short* ar2 = asb + k2*PSTR;
            #pragma unroll
            for (int s = 0; s < 3; ++s) {
                short8 bh, bl;
                ldW2(wk2 + 16*s, &bh, &bl);
                short8 av = ldA(ar2 + 16*s);
                aS_ = __builtin_amdgcn_mfma_f32_32x32x16_bf16(av, bh, aS_, 0, 0, 0);
                aS_ = __builtin_amdgcn_mfma_f32_32x32x16_bf16(av, bl, aS_, 0, 0, 0);
            }
        }
        // stats masked so the 24/32 tile overlap isn't double counted
        const float cm = (tx == 0 || m >= 8) ? 1.f : 0.f;
        #pragma unroll
        for (int r = 0; r < 16; ++r) {
            float v  = acc[t][r];
            float v2 = aS_[r];
            if (ty == 0 || r >= 4) {
                sL  = fmaf(cm, v,   sL);
                sL2 = fmaf(cm, v*v, sL2);
                sS  = fmaf(cm, v2,    sS);
                sS2 = fmaf(cm, v2*v2, sS2);
            }
            const int row = (r & 3) + 8*(r >> 2) + 4*g;  // C/D: col=lane&31
            const int ofs = (ty*24 + row)*WW + tx*24 + m;
            if (PACK) {
                pout[ofs] = (uint)(unsigned short)f2bf(v) | ((uint)(unsigned short)f2bf(v2) << 16);
            } else {
                yout[ofs] = (unsigned short)f2bf(v);
            }
        }
    }

    // ---- wave reduce + atomics (per wave = per plane) ----
    #pragma unroll
    for (int off = 32; off > 0; off >>= 1) {
        sL  += __shfl_down(sL,  off);
        sL2 += __shfl_down(sL2, off);
        sS  += __shfl_down(sS,  off);
        sS2 += __shfl_down(sS2, off);
    }
    if (lane == 0) {
        atomicAdd(&stats[c],        sL);
        atomicAdd(&stats[CC + c],   sL2);
        atomicAdd(&stats[2*CC + c], sS);
        atomicAdd(&stats[3*CC + c], sS2);
    }
}

// ---------------- Kernel 2 (packed path): pure streaming affine combine ----------------
__global__ __launch_bounds__(256) void fuse_pack_k(
    const uint* __restrict__ pk, const float* __restrict__ stats,
    const float* __restrict__ gL, const float* __restrict__ bL,
    const float* __restrict__ gS, const float* __restrict__ bS,
    float* __restrict__ out)
{
    const int bid = blockIdx.x;
    const int c   = bid % CC;
    const int tid = threadIdx.x;

    const float inv_n = 1.0f / (float)NHW;
    float mL = stats[c]          * inv_n;
    float vL = stats[CC + c]     * inv_n - mL * mL;
    float aL = rsqrtf(vL + 1e-5f) * gL[c];
    float mS = stats[2*CC + c]   * inv_n;
    float vS = stats[3*CC + c]   * inv_n - mS * mS;
    float aS = rsqrtf(vS + 1e-5f) * gS[c];
    float cst = bL[c] + bS[c] - mL * aL - mS * aS;

    const uint4* pp = (const uint4*)(pk + (size_t)bid * PLANE);
    float4*      op = (float4*)(out + (size_t)bid * PLANE);
    #pragma unroll 1
    for (int t = tid; t < PLANE/4; t += 256) {
        uint4 v = pp[t];
        float4 r;
        r.x = fmaf(aL, __uint_as_float(v.x << 16), fmaf(aS, __uint_as_float(v.x & 0xffff0000u), cst));
        r.y = fmaf(aL, __uint_as_float(v.y << 16), fmaf(aS, __uint_as_float(v.y & 0xffff0000u), cst));
        r.z = fmaf(aL, __uint_as_float(v.z << 16), fmaf(aS, __uint_as_float(v.z & 0xffff0000u), cst));
        r.w = fmaf(aL, __uint_as_float(v.w << 16), fmaf(aS, __uint_as_float(v.w & 0xffff0000u), cst));
        op[t] = r;
    }
}

// ---------------- Kernel 2 (fallback, ws too small): fp32 5x5 + affine ----------------
#define ST3 61
__global__ __launch_bounds__(256) void fuse_small_k(
    const float* __restrict__ x, const float* __restrict__ wS,
    const unsigned short* __restrict__ yL, const float* __restrict__ stats,
    const float* __restrict__ gL, const float* __restrict__ bL,
    const float* __restrict__ gS, const float* __restrict__ bS,
    float* __restrict__ out)
{
    __shared__ float in_s[60 * ST3];

    const int bid = blockIdx.x;
    const int c   = bid % CC;
    const int tid = threadIdx.x;
    const float* __restrict__ w2 = wS + c * 25;

    for (int i = tid; i < 60 * ST3; i += 256) in_s[i] = 0.f;
    __syncthreads();

    const float4* xp4 = (const float4*)(x + (size_t)bid * PLANE);
    for (int t = tid; t < PLANE / 4; t += 256) {
        int r  = t / (WW / 4);
        int c4 = (t - r * (WW / 4)) * 4;
        float4 v = xp4[t];
        float* dst = &in_s[(r + 2) * ST3 + 2 + c4];
        dst[0] = v.x; dst[1] = v.y; dst[2] = v.z; dst[3] = v.w;
    }
    __syncthreads();

    const float inv_n = 1.0f / (float)NHW;
    float mL = stats[c]          * inv_n;
    float vL = stats[CC + c]     * inv_n - mL * mL;
    float aL = rsqrtf(vL + 1e-5f) * gL[c];
    float mS = stats[2*CC + c]   * inv_n;
    float vS = stats[3*CC + c]   * inv_n - mS * mS;
    float aS = rsqrtf(vS + 1e-5f) * gS[c];
    float cst = bL[c] + bS[c] - mL * aL - mS * aS;

    const unsigned short* yp = yL + (size_t)bid * PLANE;
    float* op = out + (size_t)bid * PLANE;

    #pragma unroll 1
    for (int t = tid; t < PLANE / 4; t += 256) {
        int r  = t / 14;
        int c4 = (t - r * 14) * 4;
        float o0 = 0.f, o1 = 0.f, o2 = 0.f, o3 = 0.f;
        #pragma unroll
        for (int ky = 0; ky < 5; ++ky) {
            const float* rp = &in_s[(r + ky) * ST3 + c4];
            float f[9];
            #pragma unroll
            for (int j = 0; j < 9; ++j) f[j] = rp[j];
            const float* wr = w2 + ky * 5;
            #pragma unroll
            for (int kx = 0; kx < 5; ++kx) {
                float wv = wr[kx];
                o0 = fmaf(f[kx + 0], wv, o0);
                o1 = fmaf(f[kx + 1], wv, o1);
                o2 = fmaf(f[kx + 2], wv, o2);
                o3 = fmaf(f[kx + 3], wv, o3);
            }
        }
        ushort4 yv = *(const ushort4*)(yp + 4 * t);
        float4 res;
        res.x = fmaf(aL, __uint_as_float(((uint)yv.x) << 16), fmaf(aS, o0, cst));
        res.y = fmaf(aL, __uint_as_float(((uint)yv.y) << 16), fmaf(aS, o1, cst));
        res.z = fmaf(aL, __uint_as_float(((uint)yv.z) << 16), fmaf(aS, o2, cst));
        res.w = fmaf(aL, __uint_as_float(((uint)yv.w) << 16), fmaf(aS, o3, cst));
        *(float4*)(op + 4 * t) = res;
    }
}

extern "C" void kernel_launch(void* const* d_in, const int* in_sizes, int n_in,
                              void* d_out, int out_size, void* d_ws, size_t ws_size,
                              hipStream_t stream) {
    const float* x  = (const float*)d_in[0];
    const float* wL = (const float*)d_in[1];
    const float* gL = (const float*)d_in[2];
    const float* bL = (const float*)d_in[3];
    const float* wS = (const float*)d_in[4];
    const float* gS = (const float*)d_in[5];
    const float* bS = (const float*)d_in[6];
    float* out = (float*)d_out;

    const size_t pk_bytes = (size_t)BB * CC * PLANE * sizeof(uint);           // 77 MB
    const size_t yl_bytes = (size_t)BB * CC * PLANE * sizeof(unsigned short); // 38.5 MB
    const bool pack = ws_size >= pk_bytes + 4 * CC * sizeof(float);

    if (pack) {
        uint* pkbuf  = (uint*)d_ws;
        float* stats = (float*)((char*)d_ws + pk_bytes);
        hipMemsetAsync(stats, 0, 4 * CC * sizeof(float), stream);
        conv_large_k<true><<<4 * CC, 256, 0, stream>>>(x, wL, wS, (unsigned short*)d_ws, pkbuf, stats);
        fuse_pack_k<<<BB * CC, 256, 0, stream>>>(pkbuf, stats, gL, bL, gS, bS, out);
    } else {
        unsigned short* yLbuf = (unsigned short*)d_ws;
        float* stats = (float*)((char*)d_ws + yl_bytes);
        hipMemsetAsync(stats, 0, 4 * CC * sizeof(float), stream);
        conv_large_k<false><<<4 * CC, 256, 0, stream>>>(x, wL, wS, yLbuf, (uint*)d_ws, stats);
        fuse_small_k<<<BB * CC, 256, 0, stream>>>(x, wS, yLbuf, stats, gL, bL, gS, bS, out);
    }
}

// Round 4
// 348.220 us; speedup vs baseline: 2.2534x; 1.3796x over previous
//
#include <hip/hip_runtime.h>
#include <hip/hip_bf16.h>

#define BB 16
#define CC 384
#define HH 56
#define WW 56
#define PLANE (HH*WW)
#define NHW (BB*PLANE)

typedef __attribute__((ext_vector_type(8)))  short short8;   // 8 bf16 (4 VGPR) MFMA frag
typedef __attribute__((ext_vector_type(16))) float f32x16;   // 32x32 MFMA accumulator
typedef unsigned int uint;

// ---------------- Kernel 1: 31x31 depthwise conv via MFMA (+5x5 conv, both stored) ----------
// per ky: out-tile[m][n] += A(in rows y0+ky-15+m, cols x0-15+k) x T_ky,
//   T_ky[k][n] = w[ky][k-n] (Toeplitz band), K=64 = 4 x mfma_f32_32x32x16_bf16.
// Weights hi+lo bf16 split (2 MFMAs per A-frag) -> only x-quantization error remains.
// Bands stored as ONE dword per element (hi | lo<<16), unpacked with v_perm_b32.
// R2 lesson: ky-loop stays unroll 1 (unroll 2 -> pipeline state spill, 3x slowdown).
// R3 lesson: the PACK epilogue (4x5x3 fully-unrolled serial-MFMA region) spilled
//   ~300 dwords/thread (FETCH 264MB/WRITE 560MB vs 80/78 real). Fixes: (a) pin
//   waves_per_eu(2,2) -- LDS caps occupancy at 2 waves/SIMD anyway, so grant the
//   allocator the full 256-VGPR budget; (b) k2 loop runtime (unroll 1) to wall off
//   load hoisting; (c) sched_barrier(0) between epilogue tiles.
#define PSTR 92                // 184 B row stride: 46 words == 14 mod 32 -> 2-way (free)
#define PROWS 86               // rows -15..70 (15 zero halo each side)
#define PSZ (PROWS*PSTR)       // 7912 shorts per plane
#define WL_W 100               // dwords per large-band ky row, idx = (k-n) + 32
#define WS_W 80                // dwords per small-band ky row, idx = (k-n) + 31

static __device__ __forceinline__ short f2bf(float f) {
    // RNE float->bf16 (finite inputs only)
    unsigned int u = __float_as_uint(f);
    unsigned int r = (u + 0x7fffu + ((u >> 16) & 1u)) >> 16;
    return (short)r;
}

static __device__ __forceinline__ short8 ldA(const short* ap) {
    // 8 contiguous bf16, 8B-aligned by construction -> 2x ds_read_b64
    union { uint u[4]; short8 v; } r;
    uint2 lo = *(const uint2*)(ap);
    uint2 hi = *(const uint2*)(ap + 4);
    r.u[0] = lo.x; r.u[1] = lo.y; r.u[2] = hi.x; r.u[3] = hi.y;
    return r.v;
}

static __device__ __forceinline__ void ldW2(const uint* p, short8* h, short8* l) {
    // 8 consecutive band dwords (dword-aligned, per-lane offset) -> ds_read2_b32 x4;
    // unpack hi band (low16s) and lo band (high16s) via v_perm_b32.
    union { uint u[4]; short8 v; } H, L;
    #pragma unroll
    for (int i = 0; i < 4; ++i) {
        uint d0 = p[2*i];
        uint d1 = p[2*i + 1];
        H.u[i] = __builtin_amdgcn_perm(d1, d0, 0x05040100u);  // [d0.b0,d0.b1,d1.b0,d1.b1]
        L.u[i] = __builtin_amdgcn_perm(d1, d0, 0x07060302u);  // [d0.b2,d0.b3,d1.b2,d1.b3]
    }
    *h = H.v; *l = L.v;
}

template<bool PACK>
__global__ __launch_bounds__(256)
__attribute__((amdgpu_waves_per_eu(2, 2)))
void conv_large_k(
    const float* __restrict__ x, const float* __restrict__ wL,
    const float* __restrict__ wS,
    unsigned short* __restrict__ yL, uint* __restrict__ pk,
    float* __restrict__ stats)
{
    __shared__ __align__(16) short planes[4*PSZ];   // 63296 B
    __shared__ __align__(16) uint  wpL[31*WL_W];    // 12400 B (hi|lo packed)
    __shared__ __align__(16) uint  wpS[5*WS_W];     //  1600 B  -> 77296 B total, 2 blk/CU

    const int bid  = blockIdx.x;
    const int c    = bid % CC;
    const int bg   = bid / CC;          // batch group 0..3
    const int tid  = threadIdx.x;
    const int w    = tid >> 6;          // wave = plane
    const int lane = tid & 63;
    const int m    = lane & 31;         // A-row / B-col / D-col lane field
    const int g    = lane >> 5;         // k-group

    // ---- wave-local zero + stage own plane (bf16, halo zeros) ----
    short* pl = planes + w*PSZ;
    {
        uint4 z = make_uint4(0,0,0,0);
        uint4* p4 = (uint4*)pl;
        #pragma unroll 1
        for (int i = lane; i < PSZ/8; i += 64) p4[i] = z;
    }
    const int b = bg*4 + w;
    const float* xp = x + ((size_t)b*CC + c)*PLANE;
    #pragma unroll 1
    for (int i = lane; i < PLANE; i += 64) {
        int r  = i / WW;
        int cc = i - r*WW;
        pl[(r + 15)*PSTR + cc + 15] = f2bf(xp[i]);
    }

    // ---- cooperative weight-band build (shared by 4 waves, same c) ----
    const float* wrow = wL + c*961;
    #pragma unroll 1
    for (int i = tid; i < 31*WL_W; i += 256) {
        int ky = i / WL_W;
        int j  = i - ky*WL_W;
        int widx = j - 32;
        uint d = 0;
        if (widx >= 0 && widx < 31) {
            float wv = wrow[ky*31 + widx];
            unsigned short hi = (unsigned short)f2bf(wv);
            float res = wv - __uint_as_float((uint)hi << 16);
            unsigned short lo = (unsigned short)f2bf(res);
            d = (uint)hi | ((uint)lo << 16);
        }
        wpL[i] = d;
    }
    const float* wrowS = wS + c*25;
    #pragma unroll 1
    for (int i = tid; i < 5*WS_W; i += 256) {
        int ky = i / WS_W;
        int j  = i - ky*WS_W;
        int widx = j - 32;
        uint d = 0;
        if (widx >= 0 && widx < 5) {
            float wv = wrowS[ky*5 + widx];
            unsigned short hi = (unsigned short)f2bf(wv);
            float res = wv - __uint_as_float((uint)hi << 16);
            unsigned short lo = (unsigned short)f2bf(res);
            d = (uint)hi | ((uint)lo << 16);
        }
        wpS[i] = d;
    }
    __syncthreads();

    // ---- per-lane bases ----
    const int  toff = 8*g - m;                 // band element base = k - n
    const uint* wLd = wpL + (toff + 32);       // >= 1
    const uint* wSd = wpS + (toff + 31);       // >= 0
    const short* abase = pl + m*PSTR + 8*g;

    f32x16 acc[4] = {};                        // tiles (ty,tx), y0/x0 = 24*ty/tx

    // ---- main loop: 31 ky x 4 Ksteps x 4 tiles x (hi,lo) = 992 MFMA ----
    #pragma unroll 1
    for (int ky = 0; ky < 31; ++ky) {
        const uint* wk = wLd + ky*WL_W;
        short8 BH[4], BL[4];
        #pragma unroll
        for (int s = 0; s < 4; ++s) ldW2(wk + 16*s, &BH[s], &BL[s]);
        const short* ar = abase + ky*PSTR;
        #pragma unroll
        for (int s = 0; s < 4; ++s) {
            short8 A4[4];
            #pragma unroll
            for (int t = 0; t < 4; ++t) {
                const int ty = t >> 1, tx = t & 1;
                A4[t] = ldA(ar + ty*(24*PSTR) + tx*24 + 16*s);
            }
            #pragma unroll
            for (int t = 0; t < 4; ++t)
                acc[t] = __builtin_amdgcn_mfma_f32_32x32x16_bf16(A4[t], BH[s], acc[t], 0, 0, 0);
            #pragma unroll
            for (int t = 0; t < 4; ++t)
                acc[t] = __builtin_amdgcn_mfma_f32_32x32x16_bf16(A4[t], BL[s], acc[t], 0, 0, 0);
        }
    }

    // ---- epilogue: per tile {5x5 hi+lo MFMA, masked stats, packed store} ----
    float sL = 0.f, sL2 = 0.f, sS = 0.f, sS2 = 0.f;
    unsigned short* yout = yL + ((size_t)b*CC + c)*PLANE;
    uint*           pout = pk + ((size_t)b*CC + c)*PLANE;

    #pragma unroll
    for (int t = 0; t < 4; ++t) {
        const int ty = t >> 1, tx = t & 1;
        __builtin_amdgcn_sched_barrier(0);     // wall: no cross-tile load hoisting
        // small conv: k = n + kx + 1 in [1,36] -> 3 Ksteps; A col base = x0 + 12 (8B-aligned)
        f32x16 aS_ = {};
        const short* asb = abase + (ty*24 + 13)*PSTR + tx*24 + 12;
        #pragma unroll 1
        for (int k2 = 0; k2 < 5; ++k2) {       // runtime loop: bounds the schedulable region
            const uint* wk2 = wSd + k2*WS_W;
            const short* ar2 = asb + k2*PSTR;
            #pragma unroll
            for (int s = 0; s < 3; ++s) {
                short8 bh, bl;
                ldW2(wk2 + 16*s, &bh, &bl);
                short8 av = ldA(ar2 + 16*s);
                aS_ = __builtin_amdgcn_mfma_f32_32x32x16_bf16(av, bh, aS_, 0, 0, 0);
                aS_ = __builtin_amdgcn_mfma_f32_32x32x16_bf16(av, bl, aS_, 0, 0, 0);
            }
        }
        // stats masked so the 24/32 tile overlap isn't double counted
        const float cm = (tx == 0 || m >= 8) ? 1.f : 0.f;
        #pragma unroll
        for (int r = 0; r < 16; ++r) {
            float v  = acc[t][r];
            float v2 = aS_[r];
            if (ty == 0 || r >= 4) {
                sL  = fmaf(cm, v,   sL);
                sL2 = fmaf(cm, v*v, sL2);
                sS  = fmaf(cm, v2,    sS);
                sS2 = fmaf(cm, v2*v2, sS2);
            }
            const int row = (r & 3) + 8*(r >> 2) + 4*g;  // C/D: col=lane&31
            const int ofs = (ty*24 + row)*WW + tx*24 + m;
            if (PACK) {
                pout[ofs] = (uint)(unsigned short)f2bf(v) | ((uint)(unsigned short)f2bf(v2) << 16);
            } else {
                yout[ofs] = (unsigned short)f2bf(v);
            }
        }
    }

    // ---- wave reduce + atomics (per wave = per plane) ----
    #pragma unroll
    for (int off = 32; off > 0; off >>= 1) {
        sL  += __shfl_down(sL,  off);
        sL2 += __shfl_down(sL2, off);
        sS  += __shfl_down(sS,  off);
        sS2 += __shfl_down(sS2, off);
    }
    if (lane == 0) {
        atomicAdd(&stats[c],        sL);
        atomicAdd(&stats[CC + c],   sL2);
        atomicAdd(&stats[2*CC + c], sS);
        atomicAdd(&stats[3*CC + c], sS2);
    }
}

// ---------------- Kernel 2 (packed path): pure streaming affine combine ----------------
__global__ __launch_bounds__(256) void fuse_pack_k(
    const uint* __restrict__ pk, const float* __restrict__ stats,
    const float* __restrict__ gL, const float* __restrict__ bL,
    const float* __restrict__ gS, const float* __restrict__ bS,
    float* __restrict__ out)
{
    const int bid = blockIdx.x;
    const int c   = bid % CC;
    const int tid = threadIdx.x;

    const float inv_n = 1.0f / (float)NHW;
    float mL = stats[c]          * inv_n;
    float vL = stats[CC + c]     * inv_n - mL * mL;
    float aL = rsqrtf(vL + 1e-5f) * gL[c];
    float mS = stats[2*CC + c]   * inv_n;
    float vS = stats[3*CC + c]   * inv_n - mS * mS;
    float aS = rsqrtf(vS + 1e-5f) * gS[c];
    float cst = bL[c] + bS[c] - mL * aL - mS * aS;

    const uint4* pp = (const uint4*)(pk + (size_t)bid * PLANE);
    float4*      op = (float4*)(out + (size_t)bid * PLANE);
    #pragma unroll 1
    for (int t = tid; t < PLANE/4; t += 256) {
        uint4 v = pp[t];
        float4 r;
        r.x = fmaf(aL, __uint_as_float(v.x << 16), fmaf(aS, __uint_as_float(v.x & 0xffff0000u), cst));
        r.y = fmaf(aL, __uint_as_float(v.y << 16), fmaf(aS, __uint_as_float(v.y & 0xffff0000u), cst));
        r.z = fmaf(aL, __uint_as_float(v.z << 16), fmaf(aS, __uint_as_float(v.z & 0xffff0000u), cst));
        r.w = fmaf(aL, __uint_as_float(v.w << 16), fmaf(aS, __uint_as_float(v.w & 0xffff0000u), cst));
        op[t] = r;
    }
}

// ---------------- Kernel 2 (fallback, ws too small): fp32 5x5 + affine ----------------
#define ST3 61
__global__ __launch_bounds__(256) void fuse_small_k(
    const float* __restrict__ x, const float* __restrict__ wS,
    const unsigned short* __restrict__ yL, const float* __restrict__ stats,
    const float* __restrict__ gL, const float* __restrict__ bL,
    const float* __restrict__ gS, const float* __restrict__ bS,
    float* __restrict__ out)
{
    __shared__ float in_s[60 * ST3];

    const int bid = blockIdx.x;
    const int c   = bid % CC;
    const int tid = threadIdx.x;
    const float* __restrict__ w2 = wS + c * 25;

    for (int i = tid; i < 60 * ST3; i += 256) in_s[i] = 0.f;
    __syncthreads();

    const float4* xp4 = (const float4*)(x + (size_t)bid * PLANE);
    for (int t = tid; t < PLANE / 4; t += 256) {
        int r  = t / (WW / 4);
        int c4 = (t - r * (WW / 4)) * 4;
        float4 v = xp4[t];
        float* dst = &in_s[(r + 2) * ST3 + 2 + c4];
        dst[0] = v.x; dst[1] = v.y; dst[2] = v.z; dst[3] = v.w;
    }
    __syncthreads();

    const float inv_n = 1.0f / (float)NHW;
    float mL = stats[c]          * inv_n;
    float vL = stats[CC + c]     * inv_n - mL * mL;
    float aL = rsqrtf(vL + 1e-5f) * gL[c];
    float mS = stats[2*CC + c]   * inv_n;
    float vS = stats[3*CC + c]   * inv_n - mS * mS;
    float aS = rsqrtf(vS + 1e-5f) * gS[c];
    float cst = bL[c] + bS[c] - mL * aL - mS * aS;

    const unsigned short* yp = yL + (size_t)bid * PLANE;
    float* op = out + (size_t)bid * PLANE;

    #pragma unroll 1
    for (int t = tid; t < PLANE / 4; t += 256) {
        int r  = t / 14;
        int c4 = (t - r * 14) * 4;
        float o0 = 0.f, o1 = 0.f, o2 = 0.f, o3 = 0.f;
        #pragma unroll
        for (int ky = 0; ky < 5; ++ky) {
            const float* rp = &in_s[(r + ky) * ST3 + c4];
            float f[9];
            #pragma unroll
            for (int j = 0; j < 9; ++j) f[j] = rp[j];
            const float* wr = w2 + ky * 5;
            #pragma unroll
            for (int kx = 0; kx < 5; ++kx) {
                float wv = wr[kx];
                o0 = fmaf(f[kx + 0], wv, o0);
                o1 = fmaf(f[kx + 1], wv, o1);
                o2 = fmaf(f[kx + 2], wv, o2);
                o3 = fmaf(f[kx + 3], wv, o3);
            }
        }
        ushort4 yv = *(const ushort4*)(yp + 4 * t);
        float4 res;
        res.x = fmaf(aL, __uint_as_float(((uint)yv.x) << 16), fmaf(aS, o0, cst));
        res.y = fmaf(aL, __uint_as_float(((uint)yv.y) << 16), fmaf(aS, o1, cst));
        res.z = fmaf(aL, __uint_as_float(((uint)yv.z) << 16), fmaf(aS, o2, cst));
        res.w = fmaf(aL, __uint_as_float(((uint)yv.w) << 16), fmaf(aS, o3, cst));
        *(float4*)(op + 4 * t) = res;
    }
}

extern "C" void kernel_launch(void* const* d_in, const int* in_sizes, int n_in,
                              void* d_out, int out_size, void* d_ws, size_t ws_size,
                              hipStream_t stream) {
    const float* x  = (const float*)d_in[0];
    const float* wL = (const float*)d_in[1];
    const float* gL = (const float*)d_in[2];
    const float* bL = (const float*)d_in[3];
    const float* wS = (const float*)d_in[4];
    const float* gS = (const float*)d_in[5];
    const float* bS = (const float*)d_in[6];
    float* out = (float*)d_out;

    const size_t pk_bytes = (size_t)BB * CC * PLANE * sizeof(uint);           // 77 MB
    const size_t yl_bytes = (size_t)BB * CC * PLANE * sizeof(unsigned short); // 38.5 MB
    const bool pack = ws_size >= pk_bytes + 4 * CC * sizeof(float);

    if (pack) {
        uint* pkbuf  = (uint*)d_ws;
        float* stats = (float*)((char*)d_ws + pk_bytes);
        hipMemsetAsync(stats, 0, 4 * CC * sizeof(float), stream);
        conv_large_k<true><<<4 * CC, 256, 0, stream>>>(x, wL, wS, (unsigned short*)d_ws, pkbuf, stats);
        fuse_pack_k<<<BB * CC, 256, 0, stream>>>(pkbuf, stats, gL, bL, gS, bS, out);
    } else {
        unsigned short* yLbuf = (unsigned short*)d_ws;
        float* stats = (float*)((char*)d_ws + yl_bytes);
        hipMemsetAsync(stats, 0, 4 * CC * sizeof(float), stream);
        conv_large_k<false><<<4 * CC, 256, 0, stream>>>(x, wL, wS, yLbuf, (uint*)d_ws, stats);
        fuse_small_k<<<BB * CC, 256, 0, stream>>>(x, wS, yLbuf, stats, gL, bL, gS, bS, out);
    }
}

// Round 5
// 339.556 us; speedup vs baseline: 2.3109x; 1.0255x over previous
//
#include <hip/hip_runtime.h>
#include <hip/hip_bf16.h>

#define BB 16
#define CC 384
#define HH 56
#define WW 56
#define PLANE (HH*WW)
#define NHW (BB*PLANE)

typedef __attribute__((ext_vector_type(8)))  short short8;   // 8 bf16 (4 VGPR) MFMA frag
typedef __attribute__((ext_vector_type(16))) float f32x16;   // 32x32 MFMA accumulator
typedef unsigned int uint;

// ---------------- Kernel 1: 31x31 depthwise conv via MFMA (+5x5 conv, both stored) ----------
// per ky: out-tile[m][n] += A(in rows y0+ky-15+m, cols x0-15+k) x T_ky,
//   T_ky[k][n] = w[ky][k-n] (Toeplitz band), K=64 = 4 x mfma_f32_32x32x16_bf16.
// Weights hi+lo bf16 split (2 MFMAs per A-frag); bands packed (hi | lo<<16), v_perm unpack.
// R2 lesson: ky-loop stays unroll 1 (unroll 2 -> pipeline-state spill, 3x slowdown).
// R3 lesson: epilogue needs walls (k2 runtime loop + sched_barrier) + waves_per_eu pin,
//   else ~300 dword/thread scratch spill.
// R4 lesson: at 2 waves/SIMD (77 KB LDS) the kernel is LATENCY-bound: no pipe >45%
//   busy yet dur 2.5x the MFMA floor. This version: 2 planes/block, 2 waves/plane
//   (wave owns one tx half, acc[2]) -> LDS 45.7 KB -> 3 blocks/CU = 3 waves/SIMD.
#define PSTR 92                // 184 B row stride: 46 words == 14 mod 32 -> 2-way (free)
#define PROWS 86               // rows -15..70 (15 zero halo each side)
#define PSZ (PROWS*PSTR)       // 7912 shorts per plane
#define WL_W 100               // dwords per large-band ky row, idx = (k-n) + 32
#define WS_W 80                // dwords per small-band ky row, idx = (k-n) + 31

static __device__ __forceinline__ short f2bf(float f) {
    // RNE float->bf16 (finite inputs only)
    unsigned int u = __float_as_uint(f);
    unsigned int r = (u + 0x7fffu + ((u >> 16) & 1u)) >> 16;
    return (short)r;
}

static __device__ __forceinline__ short8 ldA(const short* ap) {
    // 8 contiguous bf16, 8B-aligned by construction -> 2x ds_read_b64
    union { uint u[4]; short8 v; } r;
    uint2 lo = *(const uint2*)(ap);
    uint2 hi = *(const uint2*)(ap + 4);
    r.u[0] = lo.x; r.u[1] = lo.y; r.u[2] = hi.x; r.u[3] = hi.y;
    return r.v;
}

static __device__ __forceinline__ void ldW2(const uint* p, short8* h, short8* l) {
    // 8 consecutive band dwords (dword-aligned, per-lane offset) -> ds_read2_b32 x4;
    // unpack hi band (low16s) and lo band (high16s) via v_perm_b32.
    union { uint u[4]; short8 v; } H, L;
    #pragma unroll
    for (int i = 0; i < 4; ++i) {
        uint d0 = p[2*i];
        uint d1 = p[2*i + 1];
        H.u[i] = __builtin_amdgcn_perm(d1, d0, 0x05040100u);  // [d0.b0,d0.b1,d1.b0,d1.b1]
        L.u[i] = __builtin_amdgcn_perm(d1, d0, 0x07060302u);  // [d0.b2,d0.b3,d1.b2,d1.b3]
    }
    *h = H.v; *l = L.v;
}

template<bool PACK>
__global__ __launch_bounds__(256)
__attribute__((amdgpu_waves_per_eu(3)))
void conv_large_k(
    const float* __restrict__ x, const float* __restrict__ wL,
    const float* __restrict__ wS,
    unsigned short* __restrict__ yL, uint* __restrict__ pk,
    float* __restrict__ stats)
{
    __shared__ __align__(16) short planes[2*PSZ];   // 31648 B
    __shared__ __align__(16) uint  wpL[31*WL_W];    // 12400 B (hi|lo packed)
    __shared__ __align__(16) uint  wpS[5*WS_W];     //  1600 B
    __shared__ float red_s[16];                     //   -> ~45.7 KB total, 3 blk/CU

    const int bid  = blockIdx.x;
    const int c    = bid % CC;
    const int pg   = bid / CC;          // plane group 0..7
    const int tid  = threadIdx.x;
    const int w    = tid >> 6;
    const int p    = w >> 1;            // plane 0..1 within block
    const int tx   = w & 1;             // column-half this wave owns
    const int lane = tid & 63;
    const int m    = lane & 31;         // A-row / B-col / D-col lane field
    const int g    = lane >> 5;         // k-group

    // ---- zero both planes (split across all threads), then barrier, then stage ----
    {
        uint4 z = make_uint4(0,0,0,0);
        uint4* p4 = (uint4*)planes;
        #pragma unroll 1
        for (int i = tid; i < 2*PSZ/8; i += 256) p4[i] = z;
    }
    __syncthreads();

    short* pl = planes + p*PSZ;
    const int b = pg*2 + p;
    const float* xp = x + ((size_t)b*CC + c)*PLANE;
    #pragma unroll 1
    for (int i = lane + 64*tx; i < PLANE; i += 128) {   // wave pair stages its plane
        int r  = i / WW;
        int cc = i - r*WW;
        pl[(r + 15)*PSTR + cc + 15] = f2bf(xp[i]);
    }

    // ---- cooperative weight-band build (shared by all 4 waves, same c) ----
    const float* wrow = wL + c*961;
    #pragma unroll 1
    for (int i = tid; i < 31*WL_W; i += 256) {
        int ky = i / WL_W;
        int j  = i - ky*WL_W;
        int widx = j - 32;
        uint d = 0;
        if (widx >= 0 && widx < 31) {
            float wv = wrow[ky*31 + widx];
            unsigned short hi = (unsigned short)f2bf(wv);
            float res = wv - __uint_as_float((uint)hi << 16);
            unsigned short lo = (unsigned short)f2bf(res);
            d = (uint)hi | ((uint)lo << 16);
        }
        wpL[i] = d;
    }
    const float* wrowS = wS + c*25;
    #pragma unroll 1
    for (int i = tid; i < 5*WS_W; i += 256) {
        int ky = i / WS_W;
        int j  = i - ky*WS_W;
        int widx = j - 32;
        uint d = 0;
        if (widx >= 0 && widx < 5) {
            float wv = wrowS[ky*5 + widx];
            unsigned short hi = (unsigned short)f2bf(wv);
            float res = wv - __uint_as_float((uint)hi << 16);
            unsigned short lo = (unsigned short)f2bf(res);
            d = (uint)hi | ((uint)lo << 16);
        }
        wpS[i] = d;
    }
    __syncthreads();

    // ---- per-lane bases ----
    const int  toff = 8*g - m;                 // band element base = k - n
    const uint* wLd = wpL + (toff + 32);       // >= 1
    const uint* wSd = wpS + (toff + 31);       // >= 0
    const short* abase = pl + m*PSTR + 8*g + tx*24;

    f32x16 acc[2] = {};                        // tiles ty=0,1 at this wave's tx half

    // ---- main loop: 31 ky x 4 Ksteps x 2 tiles x (hi,lo) = 496 MFMA/wave ----
    #pragma unroll 1
    for (int ky = 0; ky < 31; ++ky) {
        const uint* wk = wLd + ky*WL_W;
        short8 BH[4], BL[4];
        #pragma unroll
        for (int s = 0; s < 4; ++s) ldW2(wk + 16*s, &BH[s], &BL[s]);
        const short* ar = abase + ky*PSTR;
        #pragma unroll
        for (int s = 0; s < 4; ++s) {
            short8 A0 = ldA(ar + 16*s);
            short8 A1 = ldA(ar + 24*PSTR + 16*s);
            acc[0] = __builtin_amdgcn_mfma_f32_32x32x16_bf16(A0, BH[s], acc[0], 0, 0, 0);
            acc[1] = __builtin_amdgcn_mfma_f32_32x32x16_bf16(A1, BH[s], acc[1], 0, 0, 0);
            acc[0] = __builtin_amdgcn_mfma_f32_32x32x16_bf16(A0, BL[s], acc[0], 0, 0, 0);
            acc[1] = __builtin_amdgcn_mfma_f32_32x32x16_bf16(A1, BL[s], acc[1], 0, 0, 0);
        }
    }

    // ---- epilogue: per tile {5x5 hi+lo MFMA, masked stats, packed store} ----
    float sL = 0.f, sL2 = 0.f, sS = 0.f, sS2 = 0.f;
    unsigned short* yout = yL + ((size_t)b*CC + c)*PLANE;
    uint*           pout = pk + ((size_t)b*CC + c)*PLANE;

    #pragma unroll
    for (int ty = 0; ty < 2; ++ty) {
        __builtin_amdgcn_sched_barrier(0);     // wall: no cross-tile load hoisting
        // small conv: k = n + kx + 1 in [1,36] -> 3 Ksteps; A col base = x0 + 12 (8B-aligned)
        f32x16 aS_ = {};
        const short* asb = abase - tx*24 + (ty*24 + 13)*PSTR + tx*24 + 12; // = pl+m*PSTR+8g + ...
        #pragma unroll 1
        for (int k2 = 0; k2 < 5; ++k2) {       // runtime loop: bounds the schedulable region
            const uint* wk2 = wSd + k2*WS_W;
            const short* ar2 = asb + k2*PSTR;
            #pragma unroll
            for (int s = 0; s < 3; ++s) {
                short8 bh, bl;
                ldW2(wk2 + 16*s, &bh, &bl);
                short8 av = ldA(ar2 + 16*s);
                aS_ = __builtin_amdgcn_mfma_f32_32x32x16_bf16(av, bh, aS_, 0, 0, 0);
                aS_ = __builtin_amdgcn_mfma_f32_32x32x16_bf16(av, bl, aS_, 0, 0, 0);
            }
        }
        // stats masks: tx==1 counts only cols m>=8; ty==1 counts only rows r>=4
        const float cm = (tx == 0 || m >= 8) ? 1.f : 0.f;
        #pragma unroll
        for (int r = 0; r < 16; ++r) {
            float v  = acc[ty][r];
            float v2 = aS_[r];
            if (ty == 0 || r >= 4) {
                sL  = fmaf(cm, v,   sL);
                sL2 = fmaf(cm, v*v, sL2);
                sS  = fmaf(cm, v2,    sS);
                sS2 = fmaf(cm, v2*v2, sS2);
            }
            const int row = (r & 3) + 8*(r >> 2) + 4*g;  // C/D: col=lane&31
            const int ofs = (ty*24 + row)*WW + tx*24 + m;
            if (PACK) {
                pout[ofs] = (uint)(unsigned short)f2bf(v) | ((uint)(unsigned short)f2bf(v2) << 16);
            } else {
                yout[ofs] = (unsigned short)f2bf(v);
            }
        }
    }

    // ---- block reduce 4 stats -> atomics ----
    #pragma unroll
    for (int off = 32; off > 0; off >>= 1) {
        sL  += __shfl_down(sL,  off);
        sL2 += __shfl_down(sL2, off);
        sS  += __shfl_down(sS,  off);
        sS2 += __shfl_down(sS2, off);
    }
    if (lane == 0) {
        red_s[w*4 + 0] = sL;  red_s[w*4 + 1] = sL2;
        red_s[w*4 + 2] = sS;  red_s[w*4 + 3] = sS2;
    }
    __syncthreads();
    if (tid == 0) {
        float a = 0.f, e = 0.f, d0 = 0.f, e2 = 0.f;
        #pragma unroll
        for (int i = 0; i < 4; ++i) {
            a  += red_s[i*4 + 0]; e  += red_s[i*4 + 1];
            d0 += red_s[i*4 + 2]; e2 += red_s[i*4 + 3];
        }
        atomicAdd(&stats[c],        a);
        atomicAdd(&stats[CC + c],   e);
        atomicAdd(&stats[2*CC + c], d0);
        atomicAdd(&stats[3*CC + c], e2);
    }
}

// ---------------- Kernel 2 (packed path): pure streaming affine combine ----------------
// R4 lesson: the unroll-1 dependent loop held ONE outstanding 16B load per wave ->
// ~1.3 TB/s. Now 3 unconditional loads issued back-to-back (784 = 3*256 + 16 tail).
__global__ __launch_bounds__(256) void fuse_pack_k(
    const uint* __restrict__ pk, const float* __restrict__ stats,
    const float* __restrict__ gL, const float* __restrict__ bL,
    const float* __restrict__ gS, const float* __restrict__ bS,
    float* __restrict__ out)
{
    const int bid = blockIdx.x;
    const int c   = bid % CC;
    const int tid = threadIdx.x;

    const uint4* pp = (const uint4*)(pk + (size_t)bid * PLANE);
    float4*      op = (float4*)(out + (size_t)bid * PLANE);

    uint4 v0 = pp[tid];
    uint4 v1 = pp[tid + 256];
    uint4 v2 = pp[tid + 512];

    const float inv_n = 1.0f / (float)NHW;
    float mL = stats[c]          * inv_n;
    float vL = stats[CC + c]     * inv_n - mL * mL;
    float aL = rsqrtf(vL + 1e-5f) * gL[c];
    float mS = stats[2*CC + c]   * inv_n;
    float vS = stats[3*CC + c]   * inv_n - mS * mS;
    float aS = rsqrtf(vS + 1e-5f) * gS[c];
    float cst = bL[c] + bS[c] - mL * aL - mS * aS;

    #define AFF(u) fmaf(aL, __uint_as_float((u) << 16), fmaf(aS, __uint_as_float((u) & 0xffff0000u), cst))
    float4 r0, r1, r2;
    r0.x = AFF(v0.x); r0.y = AFF(v0.y); r0.z = AFF(v0.z); r0.w = AFF(v0.w);
    r1.x = AFF(v1.x); r1.y = AFF(v1.y); r1.z = AFF(v1.z); r1.w = AFF(v1.w);
    r2.x = AFF(v2.x); r2.y = AFF(v2.y); r2.z = AFF(v2.z); r2.w = AFF(v2.w);
    op[tid]       = r0;
    op[tid + 256] = r1;
    op[tid + 512] = r2;
    if (tid < PLANE/4 - 768) {              // 16-thread tail
        uint4 v3 = pp[tid + 768];
        float4 r3;
        r3.x = AFF(v3.x); r3.y = AFF(v3.y); r3.z = AFF(v3.z); r3.w = AFF(v3.w);
        op[tid + 768] = r3;
    }
    #undef AFF
}

// ---------------- Kernel 2 (fallback, ws too small): fp32 5x5 + affine ----------------
#define ST3 61
__global__ __launch_bounds__(256) void fuse_small_k(
    const float* __restrict__ x, const float* __restrict__ wS,
    const unsigned short* __restrict__ yL, const float* __restrict__ stats,
    const float* __restrict__ gL, const float* __restrict__ bL,
    const float* __restrict__ gS, const float* __restrict__ bS,
    float* __restrict__ out)
{
    __shared__ float in_s[60 * ST3];

    const int bid = blockIdx.x;
    const int c   = bid % CC;
    const int tid = threadIdx.x;
    const float* __restrict__ w2 = wS + c * 25;

    for (int i = tid; i < 60 * ST3; i += 256) in_s[i] = 0.f;
    __syncthreads();

    const float4* xp4 = (const float4*)(x + (size_t)bid * PLANE);
    for (int t = tid; t < PLANE / 4; t += 256) {
        int r  = t / (WW / 4);
        int c4 = (t - r * (WW / 4)) * 4;
        float4 v = xp4[t];
        float* dst = &in_s[(r + 2) * ST3 + 2 + c4];
        dst[0] = v.x; dst[1] = v.y; dst[2] = v.z; dst[3] = v.w;
    }
    __syncthreads();

    const float inv_n = 1.0f / (float)NHW;
    float mL = stats[c]          * inv_n;
    float vL = stats[CC + c]     * inv_n - mL * mL;
    float aL = rsqrtf(vL + 1e-5f) * gL[c];
    float mS = stats[2*CC + c]   * inv_n;
    float vS = stats[3*CC + c]   * inv_n - mS * mS;
    float aS = rsqrtf(vS + 1e-5f) * gS[c];
    float cst = bL[c] + bS[c] - mL * aL - mS * aS;

    const unsigned short* yp = yL + (size_t)bid * PLANE;
    float* op = out + (size_t)bid * PLANE;

    #pragma unroll 1
    for (int t = tid; t < PLANE / 4; t += 256) {
        int r  = t / 14;
        int c4 = (t - r * 14) * 4;
        float o0 = 0.f, o1 = 0.f, o2 = 0.f, o3 = 0.f;
        #pragma unroll
        for (int ky = 0; ky < 5; ++ky) {
            const float* rp = &in_s[(r + ky) * ST3 + c4];
            float f[9];
            #pragma unroll
            for (int j = 0; j < 9; ++j) f[j] = rp[j];
            const float* wr = w2 + ky * 5;
            #pragma unroll
            for (int kx = 0; kx < 5; ++kx) {
                float wv = wr[kx];
                o0 = fmaf(f[kx + 0], wv, o0);
                o1 = fmaf(f[kx + 1], wv, o1);
                o2 = fmaf(f[kx + 2], wv, o2);
                o3 = fmaf(f[kx + 3], wv, o3);
            }
        }
        ushort4 yv = *(const ushort4*)(yp + 4 * t);
        float4 res;
        res.x = fmaf(aL, __uint_as_float(((uint)yv.x) << 16), fmaf(aS, o0, cst));
        res.y = fmaf(aL, __uint_as_float(((uint)yv.y) << 16), fmaf(aS, o1, cst));
        res.z = fmaf(aL, __uint_as_float(((uint)yv.z) << 16), fmaf(aS, o2, cst));
        res.w = fmaf(aL, __uint_as_float(((uint)yv.w) << 16), fmaf(aS, o3, cst));
        *(float4*)(op + 4 * t) = res;
    }
}

extern "C" void kernel_launch(void* const* d_in, const int* in_sizes, int n_in,
                              void* d_out, int out_size, void* d_ws, size_t ws_size,
                              hipStream_t stream) {
    const float* x  = (const float*)d_in[0];
    const float* wL = (const float*)d_in[1];
    const float* gL = (const float*)d_in[2];
    const float* bL = (const float*)d_in[3];
    const float* wS = (const float*)d_in[4];
    const float* gS = (const float*)d_in[5];
    const float* bS = (const float*)d_in[6];
    float* out = (float*)d_out;

    const size_t pk_bytes = (size_t)BB * CC * PLANE * sizeof(uint);           // 77 MB
    const size_t yl_bytes = (size_t)BB * CC * PLANE * sizeof(unsigned short); // 38.5 MB
    const bool pack = ws_size >= pk_bytes + 4 * CC * sizeof(float);

    if (pack) {
        uint* pkbuf  = (uint*)d_ws;
        float* stats = (float*)((char*)d_ws + pk_bytes);
        hipMemsetAsync(stats, 0, 4 * CC * sizeof(float), stream);
        conv_large_k<true><<<8 * CC, 256, 0, stream>>>(x, wL, wS, (unsigned short*)d_ws, pkbuf, stats);
        fuse_pack_k<<<BB * CC, 256, 0, stream>>>(pkbuf, stats, gL, bL, gS, bS, out);
    } else {
        unsigned short* yLbuf = (unsigned short*)d_ws;
        float* stats = (float*)((char*)d_ws + yl_bytes);
        hipMemsetAsync(stats, 0, 4 * CC * sizeof(float), stream);
        conv_large_k<false><<<8 * CC, 256, 0, stream>>>(x, wL, wS, yLbuf, (uint*)d_ws, stats);
        fuse_small_k<<<BB * CC, 256, 0, stream>>>(x, wS, yLbuf, stats, gL, bL, gS, bS, out);
    }
}

// Round 8
// 279.914 us; speedup vs baseline: 2.8033x; 1.2131x over previous
//
#include <hip/hip_runtime.h>
#include <hip/hip_bf16.h>

#define BB 16
#define CC 384
#define HH 56
#define WW 56
#define PLANE (HH*WW)
#define NHW (BB*PLANE)

typedef __attribute__((ext_vector_type(8)))  short short8;   // 8 bf16 (4 VGPR) MFMA frag
typedef __attribute__((ext_vector_type(16))) float f32x16;   // 32x32 MFMA accumulator
typedef unsigned int uint;

// ---------------- Kernel 1: 31x31 depthwise conv via MFMA (+5x5 conv, both stored) ----------
// per ky: out-tile[m][n] += A x T_ky (Toeplitz band), K=64 = 4 x mfma_f32_32x32x16_bf16.
// Single bf16 band (hi/lo split dropped): single-bf16 weights add conv-output absmax
//   ~0.004 post-BN — far below the yL/yS bf16-storage noise (0.06) that dominates.
// Band format: OVERLAPPING PAIRS — dword j = bf16(w[j-32]) | bf16(w[j-31])<<16. An
//   8-element window = dwords {j0,j0+2,j0+4,j0+6} via 2x ds_read2_b32, landing directly
//   in short8 layout. Zero unpack VALU.
// R7 lesson (off-by-one): the small conv's A col base is x0+12, so its B element is
//   w2[k-n-1]; with read bias toff+31 the build MUST use widx = j-32 (same as large).
//   R7 built with j-31 -> 1-px-shifted 5x5 (absmax 8.4 = sqrt(2) post-BN, random w).
// R2 lesson: ky-loop stays unroll 1 (unroll 2 -> pipeline-state spill, 3x slowdown).
// R3 lesson: epilogue walls (k2 runtime loop + sched_barrier) + waves_per_eu pin.
// R6 lesson: cooperative launch silently no-ops under graph capture — two-kernel only.
// Structure (R5, passed): 2 planes/block, 2 waves/plane (wave owns tx half, acc[2]),
//   LDS 45.7 KB -> 3 blocks/CU = 3 waves/SIMD.
#define PSTR 92                // 184 B row stride: 46 words == 14 mod 32 -> 2-way (free)
#define PROWS 86               // rows -15..70 (15 zero halo each side)
#define PSZ (PROWS*PSTR)       // 7912 shorts per plane
#define WL_W 100               // dwords per large-band ky row, dword j = elems (j-32, j-31)
#define WS_W 80                // dwords per small-band ky row, dword j = elems (j-32, j-31)

static __device__ __forceinline__ short f2bf(float f) {
    // RNE float->bf16 (finite inputs only)
    unsigned int u = __float_as_uint(f);
    unsigned int r = (u + 0x7fffu + ((u >> 16) & 1u)) >> 16;
    return (short)r;
}

static __device__ __forceinline__ short8 ldA(const short* ap) {
    // 8 contiguous bf16, 8B-aligned by construction -> 2x ds_read_b64
    union { uint u[4]; short8 v; } r;
    uint2 lo = *(const uint2*)(ap);
    uint2 hi = *(const uint2*)(ap + 4);
    r.u[0] = lo.x; r.u[1] = lo.y; r.u[2] = hi.x; r.u[3] = hi.y;
    return r.v;
}

static __device__ __forceinline__ short8 ldW(const uint* p) {
    // overlapping-pair band: window [e0..e0+7] = dwords {0,2,4,6} -> 2x ds_read2_b32,
    // result IS the short8 fragment (each dword = 2 consecutive bf16). No unpack.
    union { uint u[4]; short8 v; } r;
    r.u[0] = p[0]; r.u[1] = p[2]; r.u[2] = p[4]; r.u[3] = p[6];
    return r.v;
}

template<bool PACK>
__global__ __launch_bounds__(256)
__attribute__((amdgpu_waves_per_eu(3)))
void conv_large_k(
    const float* __restrict__ x, const float* __restrict__ wL,
    const float* __restrict__ wS,
    unsigned short* __restrict__ yL, uint* __restrict__ pk,
    float* __restrict__ stats)
{
    __shared__ __align__(16) short planes[2*PSZ];   // 31648 B
    __shared__ __align__(16) uint  wpL[31*WL_W];    // 12400 B (pair-packed bf16)
    __shared__ __align__(16) uint  wpS[5*WS_W];     //  1600 B
    __shared__ float red_s[16];                     //   -> ~45.7 KB total, 3 blk/CU

    const int bid  = blockIdx.x;
    const int c    = bid % CC;
    const int pg   = bid / CC;          // plane group 0..7
    const int tid  = threadIdx.x;
    const int w    = tid >> 6;
    const int p    = w >> 1;            // plane 0..1 within block
    const int tx   = w & 1;             // column-half this wave owns
    const int lane = tid & 63;
    const int m    = lane & 31;         // A-row / B-col / D-col lane field
    const int g    = lane >> 5;         // k-group

    // ---- zero both planes (halo must be 0), barrier, stage ----
    {
        uint4 z = make_uint4(0,0,0,0);
        uint4* p4 = (uint4*)planes;
        #pragma unroll 1
        for (int i = tid; i < 2*PSZ/8; i += 256) p4[i] = z;
    }
    __syncthreads();

    short* pl = planes + p*PSZ;
    const int b = pg*2 + p;
    const float4* xp4 = (const float4*)(x + ((size_t)b*CC + c)*PLANE);
    #pragma unroll 1
    for (int i4 = lane + 64*tx; i4 < PLANE/4; i4 += 128) {   // wave pair stages its plane
        float4 v = xp4[i4];
        int e  = 4*i4;
        int r  = e / WW;                 // 56 % 4 == 0: groups never cross rows
        int cc = e - r*WW;
        short* dst = &pl[(r + 15)*PSTR + cc + 15];
        dst[0] = f2bf(v.x); dst[1] = f2bf(v.y); dst[2] = f2bf(v.z); dst[3] = f2bf(v.w);
    }

    // ---- cooperative band build (pair-packed single bf16, both biased j-32) ----
    const float* wrow = wL + c*961;
    #pragma unroll 1
    for (int i = tid; i < 31*WL_W; i += 256) {
        int ky = i / WL_W;
        int j  = i - ky*WL_W;
        int widx = j - 32;
        uint lo = (widx   >= 0 && widx   < 31) ? (uint)(unsigned short)f2bf(wrow[ky*31 + widx])     : 0u;
        uint hi = (widx+1 >= 0 && widx+1 < 31) ? (uint)(unsigned short)f2bf(wrow[ky*31 + widx + 1]) : 0u;
        wpL[i] = lo | (hi << 16);
    }
    const float* wrowS = wS + c*25;
    #pragma unroll 1
    for (int i = tid; i < 5*WS_W; i += 256) {
        int ky = i / WS_W;
        int j  = i - ky*WS_W;
        int widx = j - 32;               // R7 bug was j-31 here: read bias toff+31 needs j-32
        uint lo = (widx   >= 0 && widx   < 5) ? (uint)(unsigned short)f2bf(wrowS[ky*5 + widx])     : 0u;
        uint hi = (widx+1 >= 0 && widx+1 < 5) ? (uint)(unsigned short)f2bf(wrowS[ky*5 + widx + 1]) : 0u;
        wpS[i] = lo | (hi << 16);
    }
    __syncthreads();

    // ---- per-lane bases ----
    const int  toff = 8*g - m;                 // band element base = k - n
    const uint* wLd = wpL + (toff + 32);       // elem i=0 -> k-n   (large: w[k-n])
    const uint* wSd = wpS + (toff + 31);       // elem i=0 -> k-n-1 (small: w2[k-n-1])
    const short* abase = pl + m*PSTR + 8*g + tx*24;

    f32x16 acc[2] = {};                        // tiles ty=0,1 at this wave's tx half

    // ---- main loop: 31 ky x 4 Ksteps x 2 tiles = 248 MFMA/wave ----
    #pragma unroll 1
    for (int ky = 0; ky < 31; ++ky) {
        const uint* wk = wLd + ky*WL_W;
        short8 Bv[4];
        #pragma unroll
        for (int s = 0; s < 4; ++s) Bv[s] = ldW(wk + 16*s);
        const short* ar = abase + ky*PSTR;
        #pragma unroll
        for (int s = 0; s < 4; ++s) {
            short8 A0 = ldA(ar + 16*s);
            short8 A1 = ldA(ar + 24*PSTR + 16*s);
            acc[0] = __builtin_amdgcn_mfma_f32_32x32x16_bf16(A0, Bv[s], acc[0], 0, 0, 0);
            acc[1] = __builtin_amdgcn_mfma_f32_32x32x16_bf16(A1, Bv[s], acc[1], 0, 0, 0);
        }
    }

    // ---- epilogue: per tile {5x5 MFMA, masked stats, packed store} ----
    float sL = 0.f, sL2 = 0.f, sS = 0.f, sS2 = 0.f;
    unsigned short* yout = yL + ((size_t)b*CC + c)*PLANE;
    uint*           pout = pk + ((size_t)b*CC + c)*PLANE;

    #pragma unroll
    for (int ty = 0; ty < 2; ++ty) {
        __builtin_amdgcn_sched_barrier(0);     // wall: no cross-tile load hoisting
        // small conv: A col base = x0 + 12 (8B-aligned); B elem = w2[k-n-1]
        f32x16 aS_ = {};
        const short* asb = abase + (ty*24 + 13)*PSTR + 12;
        #pragma unroll 1
        for (int k2 = 0; k2 < 5; ++k2) {       // runtime loop: bounds the schedulable region
            const uint* wk2 = wSd + k2*WS_W;
            const short* ar2 = asb + k2*PSTR;
            #pragma unroll
            for (int s = 0; s < 3; ++s) {
                short8 bs = ldW(wk2 + 16*s);
                short8 av = ldA(ar2 + 16*s);
                aS_ = __builtin_amdgcn_mfma_f32_32x32x16_bf16(av, bs, aS_, 0, 0, 0);
            }
        }
        // stats masks: tx==1 counts only cols m>=8; ty==1 counts only rows r>=4
        const float cm = (tx == 0 || m >= 8) ? 1.f : 0.f;
        #pragma unroll
        for (int r = 0; r < 16; ++r) {
            float v  = acc[ty][r];
            float v2 = aS_[r];
            if (ty == 0 || r >= 4) {
                sL  = fmaf(cm, v,   sL);
                sL2 = fmaf(cm, v*v, sL2);
                sS  = fmaf(cm, v2,    sS);
                sS2 = fmaf(cm, v2*v2, sS2);
            }
            const int row = (r & 3) + 8*(r >> 2) + 4*g;  // C/D: col=lane&31
            const int ofs = (ty*24 + row)*WW + tx*24 + m;
            if (PACK) {
                pout[ofs] = (uint)(unsigned short)f2bf(v) | ((uint)(unsigned short)f2bf(v2) << 16);
            } else {
                yout[ofs] = (unsigned short)f2bf(v);
            }
        }
    }

    // ---- block reduce 4 stats -> atomics ----
    #pragma unroll
    for (int off = 32; off > 0; off >>= 1) {
        sL  += __shfl_down(sL,  off);
        sL2 += __shfl_down(sL2, off);
        sS  += __shfl_down(sS,  off);
        sS2 += __shfl_down(sS2, off);
    }
    if (lane == 0) {
        red_s[w*4 + 0] = sL;  red_s[w*4 + 1] = sL2;
        red_s[w*4 + 2] = sS;  red_s[w*4 + 3] = sS2;
    }
    __syncthreads();
    if (tid == 0) {
        float a = 0.f, e = 0.f, d0 = 0.f, e2 = 0.f;
        #pragma unroll
        for (int i = 0; i < 4; ++i) {
            a  += red_s[i*4 + 0]; e  += red_s[i*4 + 1];
            d0 += red_s[i*4 + 2]; e2 += red_s[i*4 + 3];
        }
        atomicAdd(&stats[c],        a);
        atomicAdd(&stats[CC + c],   e);
        atomicAdd(&stats[2*CC + c], d0);
        atomicAdd(&stats[3*CC + c], e2);
    }
}

// ---------------- Kernel 2 (packed path): pure streaming affine combine ----------------
__global__ __launch_bounds__(256) void fuse_pack_k(
    const uint* __restrict__ pk, const float* __restrict__ stats,
    const float* __restrict__ gL, const float* __restrict__ bL,
    const float* __restrict__ gS, const float* __restrict__ bS,
    float* __restrict__ out)
{
    const int bid = blockIdx.x;
    const int c   = bid % CC;
    const int tid = threadIdx.x;

    const uint4* pp = (const uint4*)(pk + (size_t)bid * PLANE);
    float4*      op = (float4*)(out + (size_t)bid * PLANE);

    uint4 v0 = pp[tid];
    uint4 v1 = pp[tid + 256];
    uint4 v2 = pp[tid + 512];

    const float inv_n = 1.0f / (float)NHW;
    float mL = stats[c]          * inv_n;
    float vL = stats[CC + c]     * inv_n - mL * mL;
    float aL = rsqrtf(vL + 1e-5f) * gL[c];
    float mS = stats[2*CC + c]   * inv_n;
    float vS = stats[3*CC + c]   * inv_n - mS * mS;
    float aS = rsqrtf(vS + 1e-5f) * gS[c];
    float cst = bL[c] + bS[c] - mL * aL - mS * aS;

    #define AFF(u) fmaf(aL, __uint_as_float((u) << 16), fmaf(aS, __uint_as_float((u) & 0xffff0000u), cst))
    float4 r0, r1, r2;
    r0.x = AFF(v0.x); r0.y = AFF(v0.y); r0.z = AFF(v0.z); r0.w = AFF(v0.w);
    r1.x = AFF(v1.x); r1.y = AFF(v1.y); r1.z = AFF(v1.z); r1.w = AFF(v1.w);
    r2.x = AFF(v2.x); r2.y = AFF(v2.y); r2.z = AFF(v2.z); r2.w = AFF(v2.w);
    op[tid]       = r0;
    op[tid + 256] = r1;
    op[tid + 512] = r2;
    if (tid < PLANE/4 - 768) {              // 16-thread tail
        uint4 v3 = pp[tid + 768];
        float4 r3;
        r3.x = AFF(v3.x); r3.y = AFF(v3.y); r3.z = AFF(v3.z); r3.w = AFF(v3.w);
        op[tid + 768] = r3;
    }
    #undef AFF
}

// ---------------- Kernel 2 (fallback, ws too small): fp32 5x5 + affine ----------------
#define ST3 61
__global__ __launch_bounds__(256) void fuse_small_k(
    const float* __restrict__ x, const float* __restrict__ wS,
    const unsigned short* __restrict__ yL, const float* __restrict__ stats,
    const float* __restrict__ gL, const float* __restrict__ bL,
    const float* __restrict__ gS, const float* __restrict__ bS,
    float* __restrict__ out)
{
    __shared__ float in_s[60 * ST3];

    const int bid = blockIdx.x;
    const int c   = bid % CC;
    const int tid = threadIdx.x;
    const float* __restrict__ w2 = wS + c * 25;

    for (int i = tid; i < 60 * ST3; i += 256) in_s[i] = 0.f;
    __syncthreads();

    const float4* xp4 = (const float4*)(x + (size_t)bid * PLANE);
    for (int t = tid; t < PLANE / 4; t += 256) {
        int r  = t / (WW / 4);
        int c4 = (t - r * (WW / 4)) * 4;
        float4 v = xp4[t];
        float* dst = &in_s[(r + 2) * ST3 + 2 + c4];
        dst[0] = v.x; dst[1] = v.y; dst[2] = v.z; dst[3] = v.w;
    }
    __syncthreads();

    const float inv_n = 1.0f / (float)NHW;
    float mL = stats[c]          * inv_n;
    float vL = stats[CC + c]     * inv_n - mL * mL;
    float aL = rsqrtf(vL + 1e-5f) * gL[c];
    float mS = stats[2*CC + c]   * inv_n;
    float vS = stats[3*CC + c]   * inv_n - mS * mS;
    float aS = rsqrtf(vS + 1e-5f) * gS[c];
    float cst = bL[c] + bS[c] - mL * aL - mS * aS;

    const unsigned short* yp = yL + (size_t)bid * PLANE;
    float* op = out + (size_t)bid * PLANE;

    #pragma unroll 1
    for (int t = tid; t < PLANE / 4; t += 256) {
        int r  = t / 14;
        int c4 = (t - r * 14) * 4;
        float o0 = 0.f, o1 = 0.f, o2 = 0.f, o3 = 0.f;
        #pragma unroll
        for (int ky = 0; ky < 5; ++ky) {
            const float* rp = &in_s[(r + ky) * ST3 + c4];
            float f[9];
            #pragma unroll
            for (int j = 0; j < 9; ++j) f[j] = rp[j];
            const float* wr = w2 + ky * 5;
            #pragma unroll
            for (int kx = 0; kx < 5; ++kx) {
                float wv = wr[kx];
                o0 = fmaf(f[kx + 0], wv, o0);
                o1 = fmaf(f[kx + 1], wv, o1);
                o2 = fmaf(f[kx + 2], wv, o2);
                o3 = fmaf(f[kx + 3], wv, o3);
            }
        }
        ushort4 yv = *(const ushort4*)(yp + 4 * t);
        float4 res;
        res.x = fmaf(aL, __uint_as_float(((uint)yv.x) << 16), fmaf(aS, o0, cst));
        res.y = fmaf(aL, __uint_as_float(((uint)yv.y) << 16), fmaf(aS, o1, cst));
        res.z = fmaf(aL, __uint_as_float(((uint)yv.z) << 16), fmaf(aS, o2, cst));
        res.w = fmaf(aL, __uint_as_float(((uint)yv.w) << 16), fmaf(aS, o3, cst));
        *(float4*)(op + 4 * t) = res;
    }
}

extern "C" void kernel_launch(void* const* d_in, const int* in_sizes, int n_in,
                              void* d_out, int out_size, void* d_ws, size_t ws_size,
                              hipStream_t stream) {
    const float* x  = (const float*)d_in[0];
    const float* wL = (const float*)d_in[1];
    const float* gL = (const float*)d_in[2];
    const float* bL = (const float*)d_in[3];
    const float* wS = (const float*)d_in[4];
    const float* gS = (const float*)d_in[5];
    const float* bS = (const float*)d_in[6];
    float* out = (float*)d_out;

    const size_t pk_bytes = (size_t)BB * CC * PLANE * sizeof(uint);           // 77 MB
    const size_t yl_bytes = (size_t)BB * CC * PLANE * sizeof(unsigned short); // 38.5 MB
    const bool pack = ws_size >= pk_bytes + 4 * CC * sizeof(float);

    if (pack) {
        uint* pkbuf  = (uint*)d_ws;
        float* stats = (float*)((char*)d_ws + pk_bytes);
        hipMemsetAsync(stats, 0, 4 * CC * sizeof(float), stream);
        conv_large_k<true><<<8 * CC, 256, 0, stream>>>(x, wL, wS, (unsigned short*)d_ws, pkbuf, stats);
        fuse_pack_k<<<BB * CC, 256, 0, stream>>>(pkbuf, stats, gL, bL, gS, bS, out);
    } else {
        unsigned short* yLbuf = (unsigned short*)d_ws;
        float* stats = (float*)((char*)d_ws + yl_bytes);
        hipMemsetAsync(stats, 0, 4 * CC * sizeof(float), stream);
        conv_large_k<false><<<8 * CC, 256, 0, stream>>>(x, wL, wS, yLbuf, (uint*)d_ws, stats);
        fuse_small_k<<<BB * CC, 256, 0, stream>>>(x, wS, yLbuf, stats, gL, bL, gS, bS, out);
    }
}

// Round 10
// 273.948 us; speedup vs baseline: 2.8643x; 1.0218x over previous
//
#include <hip/hip_runtime.h>
#include <hip/hip_bf16.h>

#define BB 16
#define CC 384
#define HH 56
#define WW 56
#define PLANE (HH*WW)
#define NHW (BB*PLANE)

typedef __attribute__((ext_vector_type(8)))  short short8;   // 8 bf16 (4 VGPR) MFMA frag
typedef __attribute__((ext_vector_type(16))) float f32x16;   // 32x32 MFMA accumulator
typedef __attribute__((ext_vector_type(4)))  unsigned int uint4v;
typedef __attribute__((ext_vector_type(4)))  float float4v;
typedef unsigned int uint;

// ---------------- Kernel 1: 31x31 depthwise conv via MFMA (+5x5 conv, both stored) ----------
// per ky: out-tile[m][n] += A x T_ky (Toeplitz band), K=64 = 4 x mfma_f32_32x32x16_bf16.
// Single bf16 band; pair-packed (dword j = w[j-32],w[j-31]) -> ldW = 2x ds_read2_b32, no unpack.
// R8 lesson: at 166us no pipe >55% busy — per-ky chain {24 LDS -> wait -> 8 MFMA} exposes
//   LDS latency at every ky boundary. R9/R10: copy-free PING-PONG pipeline (manual 2-stage
//   naming A0/B0 <-> A1/B1; no rotation copies, no compiler unroll per R2).
// R9 lesson (grid math): 6144 planes / 2-planes-per-fuse-block = 3072 fuse blocks, NOT
//   conv_grid/2 = 1536. Half-covered output -> absmax = max|ref| = 8.5.
// R7 lesson: small-conv band build biased j-32 (A col base x0+12 -> B elem w2[k-n-1]).
// R3 lesson: epilogue walls (k2 runtime loop + sched_barrier) + waves_per_eu pin.
// R6 lesson: cooperative launch silently no-ops under graph capture — two-kernel only.
// Structure (R5): 2 planes/block, 2 waves/plane (wave owns tx half, acc[2]),
//   LDS 45.7 KB -> 3 blocks/CU = 3 waves/SIMD.
#define PSTR 92                // 184 B row stride: 46 words == 14 mod 32 -> 2-way (free)
#define PROWS 86               // rows -15..70 (15 zero halo each side)
#define PSZ (PROWS*PSTR)       // 7912 shorts per plane
#define WL_W 100               // dwords per large-band ky row, dword j = elems (j-32, j-31)
#define WS_W 80                // dwords per small-band ky row, dword j = elems (j-32, j-31)

static __device__ __forceinline__ short f2bf(float f) {
    // RNE float->bf16 (finite inputs only)
    unsigned int u = __float_as_uint(f);
    unsigned int r = (u + 0x7fffu + ((u >> 16) & 1u)) >> 16;
    return (short)r;
}

static __device__ __forceinline__ short8 ldA(const short* ap) {
    // 8 contiguous bf16, 8B-aligned by construction -> 2x ds_read_b64 (or merged read2)
    union { uint u[4]; short8 v; } r;
    uint2 lo = *(const uint2*)(ap);
    uint2 hi = *(const uint2*)(ap + 4);
    r.u[0] = lo.x; r.u[1] = lo.y; r.u[2] = hi.x; r.u[3] = hi.y;
    return r.v;
}

static __device__ __forceinline__ short8 ldW(const uint* p) {
    // overlapping-pair band: window [e0..e0+7] = dwords {0,2,4,6} -> 2x ds_read2_b32,
    // result IS the short8 fragment (each dword = 2 consecutive bf16). No unpack.
    union { uint u[4]; short8 v; } r;
    r.u[0] = p[0]; r.u[1] = p[2]; r.u[2] = p[4]; r.u[3] = p[6];
    return r.v;
}

template<bool PACK>
__global__ __launch_bounds__(256)
__attribute__((amdgpu_waves_per_eu(3)))
void conv_large_k(
    const float* __restrict__ x, const float* __restrict__ wL,
    const float* __restrict__ wS,
    unsigned short* __restrict__ yL, uint* __restrict__ pk,
    float* __restrict__ stats)
{
    __shared__ __align__(16) short planes[2*PSZ];   // 31648 B
    __shared__ __align__(16) uint  wpL[31*WL_W];    // 12400 B (pair-packed bf16)
    __shared__ __align__(16) uint  wpS[5*WS_W];     //  1600 B
    __shared__ float red_s[16];                     //   -> ~45.7 KB total, 3 blk/CU

    const int bid  = blockIdx.x;
    const int c    = bid % CC;
    const int pg   = bid / CC;          // plane group 0..7
    const int tid  = threadIdx.x;
    const int w    = tid >> 6;
    const int p    = w >> 1;            // plane 0..1 within block
    const int tx   = w & 1;             // column-half this wave owns
    const int lane = tid & 63;
    const int m    = lane & 31;         // A-row / B-col / D-col lane field
    const int g    = lane >> 5;         // k-group

    // ---- zero both planes (halo must be 0), barrier, stage ----
    {
        uint4 z = make_uint4(0,0,0,0);
        uint4* p4 = (uint4*)planes;
        #pragma unroll 1
        for (int i = tid; i < 2*PSZ/8; i += 256) p4[i] = z;
    }
    __syncthreads();

    short* pl = planes + p*PSZ;
    const int b = pg*2 + p;
    const float4* xp4 = (const float4*)(x + ((size_t)b*CC + c)*PLANE);
    #pragma unroll 1
    for (int i4 = lane + 64*tx; i4 < PLANE/4; i4 += 128) {   // wave pair stages its plane
        float4 v = xp4[i4];
        int e  = 4*i4;
        int r  = e / WW;                 // 56 % 4 == 0: groups never cross rows
        int cc = e - r*WW;
        short* dst = &pl[(r + 15)*PSTR + cc + 15];
        dst[0] = f2bf(v.x); dst[1] = f2bf(v.y); dst[2] = f2bf(v.z); dst[3] = f2bf(v.w);
    }

    // ---- cooperative band build (pair-packed single bf16, both biased j-32) ----
    const float* wrow = wL + c*961;
    #pragma unroll 1
    for (int i = tid; i < 31*WL_W; i += 256) {
        int ky = i / WL_W;
        int j  = i - ky*WL_W;
        int widx = j - 32;
        uint lo = (widx   >= 0 && widx   < 31) ? (uint)(unsigned short)f2bf(wrow[ky*31 + widx])     : 0u;
        uint hi = (widx+1 >= 0 && widx+1 < 31) ? (uint)(unsigned short)f2bf(wrow[ky*31 + widx + 1]) : 0u;
        wpL[i] = lo | (hi << 16);
    }
    const float* wrowS = wS + c*25;
    #pragma unroll 1
    for (int i = tid; i < 5*WS_W; i += 256) {
        int ky = i / WS_W;
        int j  = i - ky*WS_W;
        int widx = j - 32;               // read bias toff+31 needs j-32 (R7 lesson)
        uint lo = (widx   >= 0 && widx   < 5) ? (uint)(unsigned short)f2bf(wrowS[ky*5 + widx])     : 0u;
        uint hi = (widx+1 >= 0 && widx+1 < 5) ? (uint)(unsigned short)f2bf(wrowS[ky*5 + widx + 1]) : 0u;
        wpS[i] = lo | (hi << 16);
    }
    __syncthreads();

    // ---- per-lane bases ----
    const int  toff = 8*g - m;                 // band element base = k - n
    const uint* wLd = wpL + (toff + 32);       // elem i=0 -> k-n   (large: w[k-n])
    const uint* wSd = wpS + (toff + 31);       // elem i=0 -> k-n-1 (small: w2[k-n-1])
    const short* abase = pl + m*PSTR + 8*g + tx*24;

    f32x16 acc[2] = {};                        // tiles ty=0,1 at this wave's tx half

    // ---- main loop: ping-pong pipelined, 31 ky x 4 Ksteps x 2 tiles = 248 MFMA/wave ----
    short8 A0[8], B0[4], A1[8], B1[4];
    {   // prologue: ky=0 into set 0
        #pragma unroll
        for (int s = 0; s < 4; ++s) B0[s] = ldW(wLd + 16*s);
        #pragma unroll
        for (int s = 0; s < 4; ++s) {
            A0[2*s]   = ldA(abase + 16*s);
            A0[2*s+1] = ldA(abase + 24*PSTR + 16*s);
        }
    }
    #pragma unroll 1
    for (int ky = 0; ky < 30; ky += 2) {
        {   // stage 1: prefetch ky+1 into set 1; consume set 0 (= ky)
            const uint* wk = wLd + (ky+1)*WL_W;
            const short* ar = abase + (ky+1)*PSTR;
            #pragma unroll
            for (int s = 0; s < 4; ++s) B1[s] = ldW(wk + 16*s);
            #pragma unroll
            for (int s = 0; s < 4; ++s) {
                A1[2*s]   = ldA(ar + 16*s);
                A1[2*s+1] = ldA(ar + 24*PSTR + 16*s);
            }
            #pragma unroll
            for (int s = 0; s < 4; ++s) {
                acc[0] = __builtin_amdgcn_mfma_f32_32x32x16_bf16(A0[2*s],   B0[s], acc[0], 0, 0, 0);
                acc[1] = __builtin_amdgcn_mfma_f32_32x32x16_bf16(A0[2*s+1], B0[s], acc[1], 0, 0, 0);
            }
        }
        {   // stage 2: prefetch ky+2 into set 0; consume set 1 (= ky+1)
            const uint* wk = wLd + (ky+2)*WL_W;
            const short* ar = abase + (ky+2)*PSTR;
            #pragma unroll
            for (int s = 0; s < 4; ++s) B0[s] = ldW(wk + 16*s);
            #pragma unroll
            for (int s = 0; s < 4; ++s) {
                A0[2*s]   = ldA(ar + 16*s);
                A0[2*s+1] = ldA(ar + 24*PSTR + 16*s);
            }
            #pragma unroll
            for (int s = 0; s < 4; ++s) {
                acc[0] = __builtin_amdgcn_mfma_f32_32x32x16_bf16(A1[2*s],   B1[s], acc[0], 0, 0, 0);
                acc[1] = __builtin_amdgcn_mfma_f32_32x32x16_bf16(A1[2*s+1], B1[s], acc[1], 0, 0, 0);
            }
        }
    }
    // tail: ky = 30 (loaded by last stage 2)
    #pragma unroll
    for (int s = 0; s < 4; ++s) {
        acc[0] = __builtin_amdgcn_mfma_f32_32x32x16_bf16(A0[2*s],   B0[s], acc[0], 0, 0, 0);
        acc[1] = __builtin_amdgcn_mfma_f32_32x32x16_bf16(A0[2*s+1], B0[s], acc[1], 0, 0, 0);
    }

    // ---- epilogue: per tile {5x5 MFMA, masked stats, packed store} ----
    float sL = 0.f, sL2 = 0.f, sS = 0.f, sS2 = 0.f;
    unsigned short* yout = yL + ((size_t)b*CC + c)*PLANE;
    uint*           pout = pk + ((size_t)b*CC + c)*PLANE;

    #pragma unroll
    for (int ty = 0; ty < 2; ++ty) {
        __builtin_amdgcn_sched_barrier(0);     // wall: no cross-tile load hoisting
        // small conv: A col base = x0 + 12 (8B-aligned); B elem = w2[k-n-1]
        f32x16 aS_ = {};
        const short* asb = abase + (ty*24 + 13)*PSTR + 12;
        #pragma unroll 1
        for (int k2 = 0; k2 < 5; ++k2) {       // runtime loop: bounds the schedulable region
            const uint* wk2 = wSd + k2*WS_W;
            const short* ar2 = asb + k2*PSTR;
            #pragma unroll
            for (int s = 0; s < 3; ++s) {
                short8 bs = ldW(wk2 + 16*s);
                short8 av = ldA(ar2 + 16*s);
                aS_ = __builtin_amdgcn_mfma_f32_32x32x16_bf16(av, bs, aS_, 0, 0, 0);
            }
        }
        // stats masks: tx==1 counts only cols m>=8; ty==1 counts only rows r>=4
        const float cm = (tx == 0 || m >= 8) ? 1.f : 0.f;
        #pragma unroll
        for (int r = 0; r < 16; ++r) {
            float v  = acc[ty][r];
            float v2 = aS_[r];
            if (ty == 0 || r >= 4) {
                sL  = fmaf(cm, v,   sL);
                sL2 = fmaf(cm, v*v, sL2);
                sS  = fmaf(cm, v2,    sS);
                sS2 = fmaf(cm, v2*v2, sS2);
            }
            const int row = (r & 3) + 8*(r >> 2) + 4*g;  // C/D: col=lane&31
            const int ofs = (ty*24 + row)*WW + tx*24 + m;
            if (PACK) {
                pout[ofs] = (uint)(unsigned short)f2bf(v) | ((uint)(unsigned short)f2bf(v2) << 16);
            } else {
                yout[ofs] = (unsigned short)f2bf(v);
            }
        }
    }

    // ---- block reduce 4 stats -> atomics ----
    #pragma unroll
    for (int off = 32; off > 0; off >>= 1) {
        sL  += __shfl_down(sL,  off);
        sL2 += __shfl_down(sL2, off);
        sS  += __shfl_down(sS,  off);
        sS2 += __shfl_down(sS2, off);
    }
    if (lane == 0) {
        red_s[w*4 + 0] = sL;  red_s[w*4 + 1] = sL2;
        red_s[w*4 + 2] = sS;  red_s[w*4 + 3] = sS2;
    }
    __syncthreads();
    if (tid == 0) {
        float a = 0.f, e = 0.f, d0 = 0.f, e2 = 0.f;
        #pragma unroll
        for (int i = 0; i < 4; ++i) {
            a  += red_s[i*4 + 0]; e  += red_s[i*4 + 1];
            d0 += red_s[i*4 + 2]; e2 += red_s[i*4 + 3];
        }
        atomicAdd(&stats[c],        a);
        atomicAdd(&stats[CC + c],   e);
        atomicAdd(&stats[2*CC + c], d0);
        atomicAdd(&stats[3*CC + c], e2);
    }
}

// ---------------- Kernel 2 (packed path): pure streaming affine combine ----------------
// 2 planes/block: grid = BB*CC/2 = 3072 (R9 lesson: plane count / 2, NOT conv grid / 2).
// Pair (bid, bid+3072): 3072 % CC == 0 -> same channel, coeffs computed once.
// 6 nontemporal loads in flight, nontemporal stores (out is write-once).
__global__ __launch_bounds__(256) void fuse_pack_k(
    const uint* __restrict__ pk, const float* __restrict__ stats,
    const float* __restrict__ gL, const float* __restrict__ bL,
    const float* __restrict__ gS, const float* __restrict__ bS,
    float* __restrict__ out)
{
    const int bid = blockIdx.x;          // 0..3071
    const int c   = bid % CC;
    const int tid = threadIdx.x;

    const uint4v* pp0 = (const uint4v*)(pk + (size_t)bid * PLANE);
    const uint4v* pp1 = (const uint4v*)(pk + ((size_t)bid + 3072) * PLANE);
    float4v* op0 = (float4v*)(out + (size_t)bid * PLANE);
    float4v* op1 = (float4v*)(out + ((size_t)bid + 3072) * PLANE);

    uint4v v0 = __builtin_nontemporal_load(pp0 + tid);
    uint4v v1 = __builtin_nontemporal_load(pp0 + tid + 256);
    uint4v v2 = __builtin_nontemporal_load(pp0 + tid + 512);
    uint4v v3 = __builtin_nontemporal_load(pp1 + tid);
    uint4v v4 = __builtin_nontemporal_load(pp1 + tid + 256);
    uint4v v5 = __builtin_nontemporal_load(pp1 + tid + 512);

    const float inv_n = 1.0f / (float)NHW;
    float mL = stats[c]          * inv_n;
    float vL = stats[CC + c]     * inv_n - mL * mL;
    float aL = rsqrtf(vL + 1e-5f) * gL[c];
    float mS = stats[2*CC + c]   * inv_n;
    float vS = stats[3*CC + c]   * inv_n - mS * mS;
    float aS = rsqrtf(vS + 1e-5f) * gS[c];
    float cst = bL[c] + bS[c] - mL * aL - mS * aS;

    #define AFF(u) fmaf(aL, __uint_as_float((u) << 16), fmaf(aS, __uint_as_float((u) & 0xffff0000u), cst))
    #define AFF4(dst, src) { float4v t_; t_[0]=AFF(src[0]); t_[1]=AFF(src[1]); t_[2]=AFF(src[2]); t_[3]=AFF(src[3]); dst = t_; }
    float4v r;
    AFF4(r, v0); __builtin_nontemporal_store(r, op0 + tid);
    AFF4(r, v1); __builtin_nontemporal_store(r, op0 + tid + 256);
    AFF4(r, v2); __builtin_nontemporal_store(r, op0 + tid + 512);
    AFF4(r, v3); __builtin_nontemporal_store(r, op1 + tid);
    AFF4(r, v4); __builtin_nontemporal_store(r, op1 + tid + 256);
    AFF4(r, v5); __builtin_nontemporal_store(r, op1 + tid + 512);
    if (tid < PLANE/4 - 768) {              // 16-thread tail per plane
        uint4v t0 = __builtin_nontemporal_load(pp0 + tid + 768);
        uint4v t1 = __builtin_nontemporal_load(pp1 + tid + 768);
        AFF4(r, t0); __builtin_nontemporal_store(r, op0 + tid + 768);
        AFF4(r, t1); __builtin_nontemporal_store(r, op1 + tid + 768);
    }
    #undef AFF4
    #undef AFF
}

// ---------------- Kernel 2 (fallback, ws too small): fp32 5x5 + affine ----------------
#define ST3 61
__global__ __launch_bounds__(256) void fuse_small_k(
    const float* __restrict__ x, const float* __restrict__ wS,
    const unsigned short* __restrict__ yL, const float* __restrict__ stats,
    const float* __restrict__ gL, const float* __restrict__ bL,
    const float* __restrict__ gS, const float* __restrict__ bS,
    float* __restrict__ out)
{
    __shared__ float in_s[60 * ST3];

    const int bid = blockIdx.x;
    const int c   = bid % CC;
    const int tid = threadIdx.x;
    const float* __restrict__ w2 = wS + c * 25;

    for (int i = tid; i < 60 * ST3; i += 256) in_s[i] = 0.f;
    __syncthreads();

    const float4* xp4 = (const float4*)(x + (size_t)bid * PLANE);
    for (int t = tid; t < PLANE / 4; t += 256) {
        int r  = t / (WW / 4);
        int c4 = (t - r * (WW / 4)) * 4;
        float4 v = xp4[t];
        float* dst = &in_s[(r + 2) * ST3 + 2 + c4];
        dst[0] = v.x; dst[1] = v.y; dst[2] = v.z; dst[3] = v.w;
    }
    __syncthreads();

    const float inv_n = 1.0f / (float)NHW;
    float mL = stats[c]          * inv_n;
    float vL = stats[CC + c]     * inv_n - mL * mL;
    float aL = rsqrtf(vL + 1e-5f) * gL[c];
    float mS = stats[2*CC + c]   * inv_n;
    float vS = stats[3*CC + c]   * inv_n - mS * mS;
    float aS = rsqrtf(vS + 1e-5f) * gS[c];
    float cst = bL[c] + bS[c] - mL * aL - mS * aS;

    const unsigned short* yp = yL + (size_t)bid * PLANE;
    float* op = out + (size_t)bid * PLANE;

    #pragma unroll 1
    for (int t = tid; t < PLANE / 4; t += 256) {
        int r  = t / 14;
        int c4 = (t - r * 14) * 4;
        float o0 = 0.f, o1 = 0.f, o2 = 0.f, o3 = 0.f;
        #pragma unroll
        for (int ky = 0; ky < 5; ++ky) {
            const float* rp = &in_s[(r + ky) * ST3 + c4];
            float f[9];
            #pragma unroll
            for (int j = 0; j < 9; ++j) f[j] = rp[j];
            const float* wr = w2 + ky * 5;
            #pragma unroll
            for (int kx = 0; kx < 5; ++kx) {
                float wv = wr[kx];
                o0 = fmaf(f[kx + 0], wv, o0);
                o1 = fmaf(f[kx + 1], wv, o1);
                o2 = fmaf(f[kx + 2], wv, o2);
                o3 = fmaf(f[kx + 3], wv, o3);
            }
        }
        ushort4 yv = *(const ushort4*)(yp + 4 * t);
        float4 res;
        res.x = fmaf(aL, __uint_as_float(((uint)yv.x) << 16), fmaf(aS, o0, cst));
        res.y = fmaf(aL, __uint_as_float(((uint)yv.y) << 16), fmaf(aS, o1, cst));
        res.z = fmaf(aL, __uint_as_float(((uint)yv.z) << 16), fmaf(aS, o2, cst));
        res.w = fmaf(aL, __uint_as_float(((uint)yv.w) << 16), fmaf(aS, o3, cst));
        *(float4*)(op + 4 * t) = res;
    }
}

extern "C" void kernel_launch(void* const* d_in, const int* in_sizes, int n_in,
                              void* d_out, int out_size, void* d_ws, size_t ws_size,
                              hipStream_t stream) {
    const float* x  = (const float*)d_in[0];
    const float* wL = (const float*)d_in[1];
    const float* gL = (const float*)d_in[2];
    const float* bL = (const float*)d_in[3];
    const float* wS = (const float*)d_in[4];
    const float* gS = (const float*)d_in[5];
    const float* bS = (const float*)d_in[6];
    float* out = (float*)d_out;

    const size_t pk_bytes = (size_t)BB * CC * PLANE * sizeof(uint);           // 77 MB
    const size_t yl_bytes = (size_t)BB * CC * PLANE * sizeof(unsigned short); // 38.5 MB
    const bool pack = ws_size >= pk_bytes + 4 * CC * sizeof(float);

    if (pack) {
        uint* pkbuf  = (uint*)d_ws;
        float* stats = (float*)((char*)d_ws + pk_bytes);
        hipMemsetAsync(stats, 0, 4 * CC * sizeof(float), stream);
        conv_large_k<true><<<8 * CC, 256, 0, stream>>>(x, wL, wS, (unsigned short*)d_ws, pkbuf, stats);
        fuse_pack_k<<<BB * CC / 2, 256, 0, stream>>>(pkbuf, stats, gL, bL, gS, bS, out);
    } else {
        unsigned short* yLbuf = (unsigned short*)d_ws;
        float* stats = (float*)((char*)d_ws + yl_bytes);
        hipMemsetAsync(stats, 0, 4 * CC * sizeof(float), stream);
        conv_large_k<false><<<8 * CC, 256, 0, stream>>>(x, wL, wS, yLbuf, (uint*)d_ws, stats);
        fuse_small_k<<<BB * CC, 256, 0, stream>>>(x, wS, yLbuf, stats, gL, bL, gS, bS, out);
    }
}